// Round 6
// baseline (203.910 us; speedup 1.0000x reference)
//
#include <hip/hip_runtime.h>
#include <math.h>

#define NCLS 80
#define PRE_K 400
#define MAX_BOXES 200
#define KEEP_CAP 200
#define N_TOT 16128
#define M_FIN (NCLS * KEEP_CAP)   // 16000
#define NMS_T 0.6f
#define NTHR 512
#define CAP 512                    // candidate buffer (>= K + tie margin)

typedef unsigned long long u64;
typedef unsigned int u32;
typedef unsigned short u16;

__device__ __forceinline__ float sigf(float x) { return 1.0f / (1.0f + expf(-x)); }

// exact score recompute — bitwise-identical expression to decode_kernel's store
__device__ __forceinline__ float score_f32(int idx, int b, int c,
    const float* __restrict__ p3, const float* __restrict__ p4, const float* __restrict__ p5)
{
    const float* base; int W, n;
    if (idx < 12288)      { base = p3; W = 64; n = idx; }
    else if (idx < 15360) { base = p4; W = 32; n = idx - 12288; }
    else                  { base = p5; W = 16; n = idx - 15360; }
    int a = n % 3, hw = n / 3, w = hw % W, h = hw / W;
    const float* rec = base + (((b * W + h) * W + w) * 255 + a * 85);
    return sigf(rec[5 + c]) * sigf(rec[4]);
}

// wave-aggregated LDS histogram add: one atomic per distinct digit per wave
__device__ __forceinline__ void hist_agg(u32* hist, u32 d, bool valid, int lane)
{
    u64 act = __ballot(valid);
    while (act) {
        int ldr = __ffsll((unsigned long long)act) - 1;
        u32 dl = __shfl(d, ldr, 64);
        u64 m = __ballot(valid && d == dl);
        if (lane == ldr) atomicAdd(&hist[dl], (u32)__popcll(m));
        act &= ~m;
    }
}

// hist[256] -> digit d with S_d >= need > S_{d+1}; wave 0 only, 1 barrier.
__device__ __forceinline__ void digit_select(const u32* hist, int need,
                                             u32* sh_dg, u32* sh_S1, u32* sh_T, int tid)
{
    if (tid < 64) {
        const int lane = tid;
        u32 h0 = hist[4 * lane + 0], h1 = hist[4 * lane + 1];
        u32 h2 = hist[4 * lane + 2], h3 = hist[4 * lane + 3];
        u32 loc = h0 + h1 + h2 + h3;
        u32 s = loc;
#pragma unroll
        for (int off = 1; off < 64; off <<= 1) {
            u32 t = __shfl_down(s, off, 64);
            if (lane + off < 64) s += t;
        }
        u32 after = s - loc;
        u32 S3 = h3 + after, S2 = h2 + S3, S1v = h1 + S2, S0 = h0 + S1v;
        u32 Sarr[5] = { S0, S1v, S2, S3, after };
#pragma unroll
        for (int k = 0; k < 4; ++k) {
            if ((int)Sarr[k] >= need && need > (int)Sarr[k + 1]) {
                *sh_dg = (u32)(4 * lane + k);
                *sh_S1 = Sarr[k + 1];
                *sh_T  = Sarr[k] - Sarr[k + 1];
            }
        }
    }
    __syncthreads();
}

// bitonic sort CAP=512 desc over LDS cand, one elem/thread; k<=64 stages in-wave
__device__ __forceinline__ void sort512(u64* cand, int tid)
{
    u64 v = cand[tid];
#pragma unroll
    for (int k2 = 2; k2 <= 64; k2 <<= 1) {
#pragma unroll
        for (int j = k2 >> 1; j > 0; j >>= 1) {
            u64 p = __shfl_xor(v, j, 64);
            bool takeMax = ((tid & k2) == 0) ^ ((tid & j) != 0);
            v = takeMax ? (v >= p ? v : p) : (v <= p ? v : p);
        }
    }
    for (int k2 = 128; k2 <= CAP; k2 <<= 1) {
        for (int j = k2 >> 1; j >= 64; j >>= 1) {
            __syncthreads();
            cand[tid] = v;
            __syncthreads();
            u64 p = cand[tid ^ j];
            bool takeMax = ((tid & k2) == 0) ^ ((tid & j) != 0);
            v = takeMax ? (v >= p ? v : p) : (v <= p ? v : p);
        }
#pragma unroll
        for (int j = 32; j > 0; j >>= 1) {
            u64 p = __shfl_xor(v, j, 64);
            bool takeMax = ((tid & k2) == 0) ^ ((tid & j) != 0);
            v = takeMax ? (v >= p ? v : p) : (v <= p ? v : p);
        }
    }
    __syncthreads();
    cand[tid] = v;
    __syncthreads();
}

// ---- Stage 1: decode u16 score keys [b][c][n] + clipped boxes float4[b][n]
__global__ __launch_bounds__(256) void decode_kernel(
    const float* __restrict__ p3, const float* __restrict__ p4, const float* __restrict__ p5,
    const float* __restrict__ a3, const float* __restrict__ a4, const float* __restrict__ a5,
    u16* __restrict__ scores16, float* __restrict__ boxes)
{
    const int blk = blockIdx.x;
    const int b = blk & 7;
    const int n = ((blk >> 3) << 8) + threadIdx.x;

    const float* base; const float* anc; int logw, nn; float sx;
    if (n < 12288)      { base = p3; anc = a3; logw = 6; nn = n;         sx = 1.2f;  }
    else if (n < 15360) { base = p4; anc = a4; logw = 5; nn = n - 12288; sx = 1.1f;  }
    else                { base = p5; anc = a5; logw = 4; nn = n - 15360; sx = 1.05f; }
    const int W = 1 << logw;
    const int a = nn % 3; const int hw = nn / 3;
    const int w = hw & (W - 1); const int h = hw >> logw;
    const float winv = 1.0f / (float)W;
    const float* rec = base + ((size_t)((b * W + h) * W + w) * 255 + a * 85);

    float tx = rec[0], ty = rec[1], tw = rec[2], th = rec[3], to = rec[4];
    float sobj = sigf(to);
    float cx = (sigf(tx) * sx - 0.5f * (sx - 1.0f) + (float)w) * winv;
    float cy = (sigf(ty) * sx - 0.5f * (sx - 1.0f) + (float)h) * winv;
    float bw = expf(tw) * anc[a * 2 + 0] * (1.0f / 512.0f);   // W*stride == 512 all levels
    float bh = expf(th) * anc[a * 2 + 1] * (1.0f / 512.0f);
    float x1 = cx - 0.5f * bw, x2 = cx + 0.5f * bw;
    float y1 = cy - 0.5f * bh, y2 = cy + 0.5f * bh;
    y1 = fminf(fmaxf(y1, 0.f), 1.f); x1 = fminf(fmaxf(x1, 0.f), 1.f);
    y2 = fminf(fmaxf(y2, 0.f), 1.f); x2 = fminf(fmaxf(x2, 0.f), 1.f);
    float4 bb; bb.x = y1; bb.y = x1; bb.z = y2; bb.w = x2;
    ((float4*)boxes)[b * N_TOT + n] = bb;

    u16* sb = scores16 + (long)b * NCLS * N_TOT + n;
#pragma unroll 8
    for (int cc = 0; cc < NCLS; ++cc)
        sb[(long)cc * N_TOT] = (u16)(__float_as_uint(sigf(rec[5 + cc]) * sobj) >> 16);
}

// ---- Stage 2: per (image,class) u16-radix top-400 -> sort -> lazy chunked NMS
__global__ __launch_bounds__(NTHR, 6) void topk_nms_fused(
    const u16* __restrict__ scores16, const float* __restrict__ boxes,
    const float* __restrict__ p3, const float* __restrict__ p4, const float* __restrict__ p5,
    float* __restrict__ ksc, float* __restrict__ kbox)
{
    __shared__ alignas(16) u64 cand[CAP];       // 4096 B
    __shared__ u32 hist[260];                   // 1040 B
    __shared__ u32 sh_dg, sh_S1, sh_T;
    __shared__ int sh_gcnt;
    __shared__ alignas(16) float boxbuf[5 * 448];   // 8960 B (also trim scratch)
    __shared__ alignas(16) u64 supc[64 * 7];        // 3584 B (per-chunk sup rows)
    __shared__ u64 keepw[7];
    __shared__ int wpre[8];
    __shared__ int sh_ncnt;

    float* by1 = boxbuf;
    float* bx1 = boxbuf + 448;
    float* by2 = boxbuf + 896;
    float* bx2 = boxbuf + 1344;
    float* bar = boxbuf + 1792;

    const int tid = threadIdx.x;
    const int wv = tid >> 6;
    const int lane = tid & 63;
    const int b = blockIdx.x & 7;     // all 80 class-blocks of an image on one XCD
    const int c = blockIdx.x >> 3;

    const u16* keys16 = scores16 + (long)(b * NCLS + c) * N_TOT;
    const uint4* k4 = (const uint4*)keys16;     // 8 u16 per load, 2016 loads
    const int N8 = N_TOT >> 3;                  // 2016

    // ---- pass 1: hi byte (concentrated -> wave-aggregated atomics)
    if (tid < 260) hist[tid] = 0u;
    if (tid == 0) sh_gcnt = 0;
    __syncthreads();
#pragma unroll
    for (int it = 0; it < 4; ++it) {
        int i4 = tid + it * NTHR;
        bool v = i4 < N8;
        u32 e0 = 0, e1 = 0, e2 = 0, e3 = 0, e4 = 0, e5 = 0, e6 = 0, e7 = 0;
        if (v) {
            uint4 kk = k4[i4];
            e0 = kk.x & 0xffffu; e1 = kk.x >> 16; e2 = kk.y & 0xffffu; e3 = kk.y >> 16;
            e4 = kk.z & 0xffffu; e5 = kk.z >> 16; e6 = kk.w & 0xffffu; e7 = kk.w >> 16;
        }
        hist_agg(hist, e0 >> 8, v, lane); hist_agg(hist, e1 >> 8, v, lane);
        hist_agg(hist, e2 >> 8, v, lane); hist_agg(hist, e3 >> 8, v, lane);
        hist_agg(hist, e4 >> 8, v, lane); hist_agg(hist, e5 >> 8, v, lane);
        hist_agg(hist, e6 >> 8, v, lane); hist_agg(hist, e7 >> 8, v, lane);
    }
    __syncthreads();

    int need = PRE_K;
    digit_select(hist, need, &sh_dg, &sh_S1, &sh_T, tid);
    u32 thr = sh_dg; need -= (int)sh_S1;
    int C = (PRE_K - need) + (int)sh_T;
    int lvl = 1;

    // ---- pass 2: low byte among hi==thr (spread -> direct atomics)
    if (C > CAP) {
        if (tid < 256) hist[tid] = 0u;
        __syncthreads();
#pragma unroll
        for (int it = 0; it < 4; ++it) {
            int i4 = tid + it * NTHR;
            if (i4 < N8) {
                uint4 kk = k4[i4];
                u32 e[8] = { kk.x & 0xffffu, kk.x >> 16, kk.y & 0xffffu, kk.y >> 16,
                             kk.z & 0xffffu, kk.z >> 16, kk.w & 0xffffu, kk.w >> 16 };
#pragma unroll
                for (int q = 0; q < 8; ++q)
                    if ((e[q] >> 8) == thr) atomicAdd(&hist[e[q] & 255u], 1u);
            }
        }
        __syncthreads();
        digit_select(hist, need, &sh_dg, &sh_S1, &sh_T, tid);
        thr = (thr << 8) | sh_dg; need -= (int)sh_S1;
        C = (PRE_K - need) + (int)sh_T;
        lvl = 2;
    }

    // ---- pass 3 (rare): refine with recomputed f32 bits [15:8]
    if (C > CAP) {
        u32 t16 = thr;
        if (tid < 256) hist[tid] = 0u;
        __syncthreads();
        for (int i = tid; i < N_TOT; i += NTHR) {
            if (keys16[i] == (u16)t16) {
                u32 kb = __float_as_uint(score_f32(i, b, c, p3, p4, p5));
                atomicAdd(&hist[(kb >> 8) & 255u], 1u);
            }
        }
        __syncthreads();
        digit_select(hist, need, &sh_dg, &sh_S1, &sh_T, tid);
        thr = (thr << 8) | sh_dg; need -= (int)sh_S1;
        C = (PRE_K - need) + (int)sh_T;
        lvl = 3;
    }

    // ---- pass 4 (rare): full 32-bit
    if (C > CAP) {
        u32 t16 = thr >> 8;
        if (tid < 256) hist[tid] = 0u;
        __syncthreads();
        for (int i = tid; i < N_TOT; i += NTHR) {
            if (keys16[i] == (u16)t16) {
                u32 kb = __float_as_uint(score_f32(i, b, c, p3, p4, p5));
                if ((kb >> 8) == thr) atomicAdd(&hist[kb & 255u], 1u);
            }
        }
        __syncthreads();
        digit_select(hist, need, &sh_dg, &sh_S1, &sh_T, tid);
        thr = (thr << 8) | sh_dg; need -= (int)sh_S1;
        C = (PRE_K - need) + (int)sh_T;
        lvl = 4;
    }

    // ---- collect candidates (superset ok; sort trims exactly)
    if (lvl <= 2) {
#pragma unroll
        for (int it = 0; it < 4; ++it) {
            int i4 = tid + it * NTHR;
            if (i4 < N8) {
                uint4 kk = k4[i4];
                int i0 = i4 << 3;
                u32 e[8] = { kk.x & 0xffffu, kk.x >> 16, kk.y & 0xffffu, kk.y >> 16,
                             kk.z & 0xffffu, kk.z >> 16, kk.w & 0xffffu, kk.w >> 16 };
#pragma unroll
                for (int q = 0; q < 8; ++q) {
                    bool take = (lvl == 1) ? ((e[q] >> 8) >= thr) : (e[q] >= thr);
                    if (take) {
                        int p = atomicAdd(&sh_gcnt, 1);
                        int i = i0 + q;
                        u32 kb = __float_as_uint(score_f32(i, b, c, p3, p4, p5));
                        cand[p] = ((u64)kb << 32) | (u32)(0xFFFFFFFFu - (u32)i);
                    }
                }
            }
        }
        __syncthreads();
        for (int t = C + tid; t < CAP; t += NTHR) cand[t] = 0ull;
    } else if (C <= CAP) {
        u32 t16 = (lvl == 3) ? (thr >> 8) : (thr >> 16);
        for (int i = tid; i < N_TOT; i += NTHR) {
            u32 k = keys16[i];
            bool take = false;
            u32 kb = 0;
            if (k > t16) { take = true; kb = __float_as_uint(score_f32(i, b, c, p3, p4, p5)); }
            else if (k == t16) {
                kb = __float_as_uint(score_f32(i, b, c, p3, p4, p5));
                take = (lvl == 3) ? ((kb >> 8) >= thr) : (kb >= thr);
            }
            if (take) {
                int p = atomicAdd(&sh_gcnt, 1);
                cand[p] = ((u64)kb << 32) | (u32)(0xFFFFFFFFu - (u32)i);
            }
        }
        __syncthreads();
        for (int t = C + tid; t < CAP; t += NTHR) cand[t] = 0ull;
    } else {
        // lvl==4 and >CAP ties at one exact f32 value: index-rank trim
        u32 t16 = thr >> 16;
        for (int i = tid; i < N_TOT; i += NTHR) {
            u32 k = keys16[i];
            if (k < t16) continue;
            u32 kb = __float_as_uint(score_f32(i, b, c, p3, p4, p5));
            if (kb > thr) {
                int p = atomicAdd(&sh_gcnt, 1);
                cand[p] = ((u64)kb << 32) | (u32)(0xFFFFFFFFu - (u32)i);
            }
        }
        __syncthreads();
        const int G = sh_gcnt;   // == PRE_K - need
        u32* scr = (u32*)boxbuf; // boxes not gathered yet
        int lo = tid * 32; if (lo > N_TOT) lo = N_TOT;
        int hi = lo + 32;  if (hi > N_TOT) hi = N_TOT;
        int lc = 0;
        for (int i = lo; i < hi; ++i)
            if (keys16[i] == (u16)t16 &&
                __float_as_uint(score_f32(i, b, c, p3, p4, p5)) == thr) ++lc;
        u32* sc_cur = scr; u32* sc_oth = scr + 512;
        sc_cur[tid] = (u32)lc;
        __syncthreads();
        for (int off = 1; off < NTHR; off <<= 1) {
            sc_oth[tid] = sc_cur[tid] + ((tid >= off) ? sc_cur[tid - off] : 0u);
            __syncthreads();
            u32* tmp = sc_cur; sc_cur = sc_oth; sc_oth = tmp;
        }
        int r = (int)sc_cur[tid] - lc;
        for (int i = lo; i < hi; ++i) {
            if (keys16[i] == (u16)t16 &&
                __float_as_uint(score_f32(i, b, c, p3, p4, p5)) == thr) {
                if (r < need) cand[G + r] = ((u64)thr << 32) | (u32)(0xFFFFFFFFu - (u32)i);
                ++r;
            }
        }
        __syncthreads();
        for (int t = PRE_K + tid; t < CAP; t += NTHR) cand[t] = 0ull;
    }
    __syncthreads();

    sort512(cand, tid);

    // ---- gather top-400 boxes (SoA, padded to 448)
    const float4* btab = (const float4*)boxes;
    for (int t = tid; t < 448; t += NTHR) {
        float y1 = 0.f, x1 = 0.f, y2 = 0.f, x2 = 0.f;
        if (t < PRE_K) {
            u64 key = cand[t];
            if ((key >> 32) != 0ull) {
                int idx = (int)(0xFFFFFFFFu - (u32)(key & 0xFFFFFFFFull));
                float4 bb = btab[b * N_TOT + idx];
                y1 = bb.x; x1 = bb.y; y2 = bb.z; x2 = bb.w;
            }
        }
        by1[t] = y1; bx1[t] = x1; by2[t] = y2; bx2[t] = x2;
        bar[t] = (y2 - y1) * (x2 - x1);
    }
    if (tid < 7) keepw[tid] = (tid < 6) ? ~0ull : 0xFFFFull;
    __syncthreads();

    // ---- lazy chunked NMS: 7 chunks of 64 rows; build rows only if still alive
    for (int ch = 0; ch < 7; ++ch) {
        const int rbase = ch << 6;
        const int nrows = (PRE_K - rbase < 64) ? (PRE_K - rbase) : 64;
        // build sup rows for alive rows in this chunk (8 waves x 8 rows)
        for (int r = wv; r < nrows; r += 8) {
            int row = rbase + r;
            if ((keepw[ch] >> r) & 1ull) {
                float ry1 = by1[row], rx1 = bx1[row], ry2 = by2[row], rx2 = bx2[row], ra = bar[row];
                for (int cw = ch; cw < 7; ++cw) {
                    int j = (cw << 6) + lane;
                    bool o = false;
                    if (j > row && j < PRE_K) {
                        float ty = fmaxf(ry1, by1[j]);
                        float tx = fmaxf(rx1, bx1[j]);
                        float by = fminf(ry2, by2[j]);
                        float rx = fminf(rx2, bx2[j]);
                        float hh = fmaxf(by - ty, 0.f);
                        float ww = fmaxf(rx - tx, 0.f);
                        float inter = hh * ww;
                        float uni = ra + bar[j] - inter;
                        o = (inter / fmaxf(uni, 1e-9f)) > NMS_T;
                    }
                    u64 m = __ballot(o);
                    if (lane == 0) supc[r * 7 + cw] = m;
                }
            }
        }
        __syncthreads();
        // greedy within chunk: single wave, keep-words in registers
        if (tid < 64) {
            u64 kw = (tid < 7) ? keepw[tid] : 0ull;
            u64 s_cur = (tid < 7) ? supc[tid] : 0ull;
            for (int r = 0; r < nrows; ++r) {
                u64 s_next = (tid < 7 && (r + 1) < nrows) ? supc[(r + 1) * 7 + tid] : 0ull;
                u64 kwv = __shfl(kw, ch);
                if (((kwv >> r) & 1ull) && tid >= ch) kw &= ~s_cur;
                s_cur = s_next;
            }
            if (tid < 7) keepw[tid] = kw;
        }
        __syncthreads();
    }

    if (tid == 0) {
        int acc = 0;
        for (int w = 0; w < 7; ++w) { wpre[w] = acc; acc += (int)__popcll(keepw[w]); }
        sh_ncnt = acc < KEEP_CAP ? acc : KEEP_CAP;
    }
    __syncthreads();

    // ---- compact kept (rank via popcount), cap 200, zero-pad
    const int blk_out = b * NCLS + c;
    float* osc = ksc + (long)blk_out * KEEP_CAP;
    float* obx = kbox + (long)blk_out * KEEP_CAP * 4;
    for (int t = tid; t < PRE_K; t += NTHR) {
        int w = t >> 6, bb = t & 63;
        u64 kwv = keepw[w];
        if ((kwv >> bb) & 1ull) {
            int pos = wpre[w] + (int)__popcll(kwv & ((1ull << bb) - 1ull));
            if (pos < KEEP_CAP) {
                osc[pos] = __uint_as_float((u32)(cand[t] >> 32));
                obx[pos * 4 + 0] = by1[t]; obx[pos * 4 + 1] = bx1[t];
                obx[pos * 4 + 2] = by2[t]; obx[pos * 4 + 3] = bx2[t];
            }
        }
    }
    for (int t = sh_ncnt + tid; t < KEEP_CAP; t += NTHR) {
        osc[t] = 0.0f;
        obx[t * 4 + 0] = 0.f; obx[t * 4 + 1] = 0.f;
        obx[t * 4 + 2] = 0.f; obx[t * 4 + 3] = 0.f;
    }
}

// ---- f32-key radix top-K (used by final_topk over compacted scores)
__device__ __forceinline__ void radix_topk_sort_f32(
    const u32* __restrict__ keys, int n, int K,
    u64* cand, u32* hist, u32* scr,
    u32* sh_dg, u32* sh_S1, u32* sh_T, int* sh_gcnt, int tid)
{
    int need = K;
    digit_select(hist, need, sh_dg, sh_S1, sh_T, tid);
    u32 thr = *sh_dg; need -= (int)*sh_S1;
    int C = (K - need) + (int)*sh_T;
    int eshift = 24;

    const uint4* k4 = (const uint4*)keys;
    const int n4 = n >> 2;
    const int nIter = (n4 + NTHR - 1) / NTHR;

    for (int shift = 16; shift >= 0 && C > CAP; shift -= 8) {
        if (tid < 256) hist[tid] = 0u;
        __syncthreads();
        for (int it = 0; it < nIter; ++it) {
            int i4 = tid + it * NTHR;
            if (i4 < n4) {
                uint4 kk = k4[i4];
                if ((kk.x >> (shift + 8)) == thr) atomicAdd(&hist[(kk.x >> shift) & 255u], 1u);
                if ((kk.y >> (shift + 8)) == thr) atomicAdd(&hist[(kk.y >> shift) & 255u], 1u);
                if ((kk.z >> (shift + 8)) == thr) atomicAdd(&hist[(kk.z >> shift) & 255u], 1u);
                if ((kk.w >> (shift + 8)) == thr) atomicAdd(&hist[(kk.w >> shift) & 255u], 1u);
            }
        }
        __syncthreads();
        digit_select(hist, need, sh_dg, sh_S1, sh_T, tid);
        thr = (thr << 8) | *sh_dg; need -= (int)*sh_S1;
        C = (K - need) + (int)*sh_T;
        eshift = shift;
    }

    if (C <= CAP) {
        for (int it = 0; it < nIter; ++it) {
            int i4 = tid + it * NTHR;
            if (i4 < n4) {
                uint4 kk = k4[i4];
                int i0 = i4 << 2;
                if ((kk.x >> eshift) >= thr) { int p = atomicAdd(sh_gcnt, 1); cand[p] = ((u64)kk.x << 32) | (u32)(0xFFFFFFFFu - (u32)(i0 + 0)); }
                if ((kk.y >> eshift) >= thr) { int p = atomicAdd(sh_gcnt, 1); cand[p] = ((u64)kk.y << 32) | (u32)(0xFFFFFFFFu - (u32)(i0 + 1)); }
                if ((kk.z >> eshift) >= thr) { int p = atomicAdd(sh_gcnt, 1); cand[p] = ((u64)kk.z << 32) | (u32)(0xFFFFFFFFu - (u32)(i0 + 2)); }
                if ((kk.w >> eshift) >= thr) { int p = atomicAdd(sh_gcnt, 1); cand[p] = ((u64)kk.w << 32) | (u32)(0xFFFFFFFFu - (u32)(i0 + 3)); }
            }
        }
        __syncthreads();
        for (int t = C + tid; t < CAP; t += NTHR) cand[t] = 0ull;
    } else {
        for (int i = tid; i < n; i += NTHR) {
            u32 k = keys[i];
            if (k > thr) {
                int p = atomicAdd(sh_gcnt, 1);
                cand[p] = ((u64)k << 32) | (u32)(0xFFFFFFFFu - (u32)i);
            }
        }
        __syncthreads();
        const int G = *sh_gcnt;
        int lo = tid * 32; if (lo > n) lo = n;
        int hi = lo + 32;  if (hi > n) hi = n;
        int lc = 0;
        for (int i = lo; i < hi; ++i) if (keys[i] == thr) ++lc;
        u32* sc_cur = scr; u32* sc_oth = scr + 512;
        sc_cur[tid] = (u32)lc;
        __syncthreads();
        for (int off = 1; off < NTHR; off <<= 1) {
            sc_oth[tid] = sc_cur[tid] + ((tid >= off) ? sc_cur[tid - off] : 0u);
            __syncthreads();
            u32* tmp = sc_cur; sc_cur = sc_oth; sc_oth = tmp;
        }
        int r = (int)sc_cur[tid] - lc;
        for (int i = lo; i < hi; ++i) {
            if (keys[i] == thr) {
                if (r < need) cand[G + r] = ((u64)thr << 32) | (u32)(0xFFFFFFFFu - (u32)i);
                ++r;
            }
        }
        __syncthreads();
        for (int t = K + tid; t < CAP; t += NTHR) cand[t] = 0ull;
    }
    __syncthreads();
    sort512(cand, tid);
}

// ---- Stage 3: per image top-200 over 16000 compacted candidates -> outputs
__global__ __launch_bounds__(NTHR) void final_topk_kernel(
    const float* __restrict__ ksc, const float* __restrict__ kbox,
    float* __restrict__ out)
{
    __shared__ alignas(16) u64 cand[CAP];
    __shared__ u32 hist[260];
    __shared__ u32 scr[1024];
    __shared__ u32 sh_dg, sh_S1, sh_T;
    __shared__ int sh_gcnt;

    const int tid = threadIdx.x;
    const int lane = tid & 63;
    const int b = blockIdx.x;
    const u32* keys = (const u32*)(ksc + (long)b * M_FIN);

    if (tid < 260) hist[tid] = 0u;
    if (tid == 0) sh_gcnt = 0;
    __syncthreads();
    const uint4* k4 = (const uint4*)keys;
#pragma unroll
    for (int it = 0; it < 8; ++it) {
        int i4 = tid + it * NTHR;
        bool v = i4 < (M_FIN >> 2);
        u32 d0 = 0, d1 = 0, d2 = 0, d3 = 0;
        if (v) {
            uint4 kk = k4[i4];
            d0 = kk.x >> 24; d1 = kk.y >> 24; d2 = kk.z >> 24; d3 = kk.w >> 24;
        }
        hist_agg(hist, d0, v, lane);
        hist_agg(hist, d1, v, lane);
        hist_agg(hist, d2, v, lane);
        hist_agg(hist, d3, v, lane);
    }
    __syncthreads();

    radix_topk_sort_f32(keys, M_FIN, MAX_BOXES, cand, hist, scr,
                        &sh_dg, &sh_S1, &sh_T, &sh_gcnt, tid);

    float* obb = out;                         // (8,200,4)
    float* ocf = out + 8 * MAX_BOXES * 4;     // (8,200)
    float* ocl = ocf + 8 * MAX_BOXES;         // (8,200)
    float* onm = ocl + 8 * MAX_BOXES;         // (8,)

    float s = 0.f;
    if (tid < MAX_BOXES) {
        u64 key = cand[tid];
        s = __uint_as_float((u32)(key >> 32));
        float y1 = 0.f, x1 = 0.f, y2 = 0.f, x2 = 0.f, cid = 0.f;
        if (s > 0.0f) {
            int i = (int)(0xFFFFFFFFu - (u32)(key & 0xFFFFFFFFull));
            int cc = i / KEEP_CAP, j = i % KEEP_CAP;
            const float* bb = kbox + (((long)b * NCLS + cc) * KEEP_CAP + j) * 4;
            y1 = bb[0]; x1 = bb[1]; y2 = bb[2]; x2 = bb[3];
            cid = (float)cc;
        }
        long o = (long)b * MAX_BOXES + tid;
        obb[o * 4 + 0] = y1; obb[o * 4 + 1] = x1; obb[o * 4 + 2] = y2; obb[o * 4 + 3] = x2;
        ocf[o] = s; ocl[o] = cid;
    }
    int cnt = __syncthreads_count(tid < MAX_BOXES && s > 0.0f);
    if (tid == 0) onm[b] = (float)cnt;
}

extern "C" void kernel_launch(void* const* d_in, const int* in_sizes, int n_in,
                              void* d_out, int out_size, void* d_ws, size_t ws_size,
                              hipStream_t stream) {
    const float* p3 = (const float*)d_in[0];
    const float* p4 = (const float*)d_in[1];
    const float* p5 = (const float*)d_in[2];
    const float* a3 = (const float*)d_in[3];
    const float* a4 = (const float*)d_in[4];
    const float* a5 = (const float*)d_in[5];
    float* out = (float*)d_out;

    const size_t s16_bytes  = (size_t)8 * NCLS * N_TOT * 2;      // 20,643,840
    const size_t box_bytes  = (size_t)8 * N_TOT * 16;            //  2,064,384
    const size_t ksc_bytes  = (size_t)8 * NCLS * KEEP_CAP * 4;   //    512,000

    u16*   scores16 = (u16*)d_ws;
    float* boxes    = (float*)((char*)d_ws + s16_bytes);
    float* ksc      = (float*)((char*)d_ws + s16_bytes + box_bytes);
    float* kbox     = (float*)((char*)d_ws + s16_bytes + box_bytes + ksc_bytes);

    decode_kernel<<<504, 256, 0, stream>>>(p3, p4, p5, a3, a4, a5, scores16, boxes);
    topk_nms_fused<<<8 * NCLS, NTHR, 0, stream>>>(scores16, boxes, p3, p4, p5, ksc, kbox);
    final_topk_kernel<<<8, NTHR, 0, stream>>>(ksc, kbox, out);
}

// Round 7
// 169.452 us; speedup vs baseline: 1.2033x; 1.2033x over previous
//
#include <hip/hip_runtime.h>
#include <math.h>

#define NCLS 80
#define PRE_K 400
#define MAX_BOXES 200
#define KEEP_CAP 200
#define N_TOT 16128
#define M_FIN (NCLS * KEEP_CAP)   // 16000
#define NMS_T 0.6f
#define NTHR 512
#define CAP 512                    // candidate buffer (>= K + tie margin)

typedef unsigned long long u64;
typedef unsigned int u32;
typedef unsigned short u16;

__device__ __forceinline__ float sigf(float x) { return 1.0f / (1.0f + expf(-x)); }

// exact score recompute — bitwise-identical expression to decode_kernel's store
__device__ __forceinline__ float score_f32(int idx, int b, int c,
    const float* __restrict__ p3, const float* __restrict__ p4, const float* __restrict__ p5)
{
    const float* base; int W, n;
    if (idx < 12288)      { base = p3; W = 64; n = idx; }
    else if (idx < 15360) { base = p4; W = 32; n = idx - 12288; }
    else                  { base = p5; W = 16; n = idx - 15360; }
    int a = n % 3, hw = n / 3, w = hw % W, h = hw / W;
    const float* rec = base + (((b * W + h) * W + w) * 255 + a * 85);
    return sigf(rec[5 + c]) * sigf(rec[4]);
}

// wave-aggregated LDS histogram add: one atomic per distinct digit per wave
__device__ __forceinline__ void hist_agg(u32* hist, u32 d, bool valid, int lane)
{
    u64 act = __ballot(valid);
    while (act) {
        int ldr = __ffsll((unsigned long long)act) - 1;
        u32 dl = __shfl(d, ldr, 64);
        u64 m = __ballot(valid && d == dl);
        if (lane == ldr) atomicAdd(&hist[dl], (u32)__popcll(m));
        act &= ~m;
    }
}

// hist[256] -> digit d with S_d >= need > S_{d+1}; wave 0 only, 1 barrier.
__device__ __forceinline__ void digit_select(const u32* hist, int need,
                                             u32* sh_dg, u32* sh_S1, u32* sh_T, int tid)
{
    if (tid < 64) {
        const int lane = tid;
        u32 h0 = hist[4 * lane + 0], h1 = hist[4 * lane + 1];
        u32 h2 = hist[4 * lane + 2], h3 = hist[4 * lane + 3];
        u32 loc = h0 + h1 + h2 + h3;
        u32 s = loc;
#pragma unroll
        for (int off = 1; off < 64; off <<= 1) {
            u32 t = __shfl_down(s, off, 64);
            if (lane + off < 64) s += t;
        }
        u32 after = s - loc;
        u32 S3 = h3 + after, S2 = h2 + S3, S1v = h1 + S2, S0 = h0 + S1v;
        u32 Sarr[5] = { S0, S1v, S2, S3, after };
#pragma unroll
        for (int k = 0; k < 4; ++k) {
            if ((int)Sarr[k] >= need && need > (int)Sarr[k + 1]) {
                *sh_dg = (u32)(4 * lane + k);
                *sh_S1 = Sarr[k + 1];
                *sh_T  = Sarr[k] - Sarr[k + 1];
            }
        }
    }
    __syncthreads();
}

// bitonic sort CAP=512 desc over LDS cand, one elem/thread; k<=64 stages in-wave
__device__ __forceinline__ void sort512(u64* cand, int tid)
{
    u64 v = cand[tid];
#pragma unroll
    for (int k2 = 2; k2 <= 64; k2 <<= 1) {
#pragma unroll
        for (int j = k2 >> 1; j > 0; j >>= 1) {
            u64 p = __shfl_xor(v, j, 64);
            bool takeMax = ((tid & k2) == 0) ^ ((tid & j) != 0);
            v = takeMax ? (v >= p ? v : p) : (v <= p ? v : p);
        }
    }
    for (int k2 = 128; k2 <= CAP; k2 <<= 1) {
        for (int j = k2 >> 1; j >= 64; j >>= 1) {
            __syncthreads();
            cand[tid] = v;
            __syncthreads();
            u64 p = cand[tid ^ j];
            bool takeMax = ((tid & k2) == 0) ^ ((tid & j) != 0);
            v = takeMax ? (v >= p ? v : p) : (v <= p ? v : p);
        }
#pragma unroll
        for (int j = 32; j > 0; j >>= 1) {
            u64 p = __shfl_xor(v, j, 64);
            bool takeMax = ((tid & k2) == 0) ^ ((tid & j) != 0);
            v = takeMax ? (v >= p ? v : p) : (v <= p ? v : p);
        }
    }
    __syncthreads();
    cand[tid] = v;
    __syncthreads();
}

// ---- Stage 1: decode u16 score keys [b][c][n] + clipped boxes float4[b][n]
__global__ __launch_bounds__(256) void decode_kernel(
    const float* __restrict__ p3, const float* __restrict__ p4, const float* __restrict__ p5,
    const float* __restrict__ a3, const float* __restrict__ a4, const float* __restrict__ a5,
    u16* __restrict__ scores16, float* __restrict__ boxes)
{
    const int blk = blockIdx.x;
    const int b = blk & 7;
    const int n = ((blk >> 3) << 8) + threadIdx.x;

    const float* base; const float* anc; int logw, nn; float sx;
    if (n < 12288)      { base = p3; anc = a3; logw = 6; nn = n;         sx = 1.2f;  }
    else if (n < 15360) { base = p4; anc = a4; logw = 5; nn = n - 12288; sx = 1.1f;  }
    else                { base = p5; anc = a5; logw = 4; nn = n - 15360; sx = 1.05f; }
    const int W = 1 << logw;
    const int a = nn % 3; const int hw = nn / 3;
    const int w = hw & (W - 1); const int h = hw >> logw;
    const float winv = 1.0f / (float)W;
    const float* rec = base + ((size_t)((b * W + h) * W + w) * 255 + a * 85);

    float tx = rec[0], ty = rec[1], tw = rec[2], th = rec[3], to = rec[4];
    float sobj = sigf(to);
    float cx = (sigf(tx) * sx - 0.5f * (sx - 1.0f) + (float)w) * winv;
    float cy = (sigf(ty) * sx - 0.5f * (sx - 1.0f) + (float)h) * winv;
    float bw = expf(tw) * anc[a * 2 + 0] * (1.0f / 512.0f);   // W*stride == 512 all levels
    float bh = expf(th) * anc[a * 2 + 1] * (1.0f / 512.0f);
    float x1 = cx - 0.5f * bw, x2 = cx + 0.5f * bw;
    float y1 = cy - 0.5f * bh, y2 = cy + 0.5f * bh;
    y1 = fminf(fmaxf(y1, 0.f), 1.f); x1 = fminf(fmaxf(x1, 0.f), 1.f);
    y2 = fminf(fmaxf(y2, 0.f), 1.f); x2 = fminf(fmaxf(x2, 0.f), 1.f);
    float4 bb; bb.x = y1; bb.y = x1; bb.z = y2; bb.w = x2;
    ((float4*)boxes)[b * N_TOT + n] = bb;

    u16* sb = scores16 + (long)b * NCLS * N_TOT + n;
#pragma unroll 8
    for (int cc = 0; cc < NCLS; ++cc)
        sb[(long)cc * N_TOT] = (u16)(__float_as_uint(sigf(rec[5 + cc]) * sobj) >> 16);
}

// ---- Stage 2: per (image,class) u16-radix top-400 -> sort -> blocked NMS
__global__ __launch_bounds__(NTHR, 4) void topk_nms_fused(
    const u16* __restrict__ scores16, const float* __restrict__ boxes,
    const float* __restrict__ p3, const float* __restrict__ p4, const float* __restrict__ p5,
    float* __restrict__ ksc, float* __restrict__ kbox)
{
    __shared__ alignas(16) u16 skey[N_TOT];          // 32256 B staged keys
    __shared__ alignas(16) u64 cand[CAP];            // 4096 B
    __shared__ u32 hist[260];                        // 1040 B
    __shared__ u32 sh_dg, sh_S1, sh_T;
    __shared__ int sh_gcnt;
    __shared__ alignas(16) float boxbuf[5 * 448];    // 8960 B (also lvl-4 trim scratch)
    __shared__ alignas(16) u64 diagbuf[64];          // 512 B
    __shared__ u32 keepb[16];                        // 448 keep bits (14 words used)
    __shared__ u64 sh_keptM;
    __shared__ int wpre14[14];
    __shared__ int sh_ncnt;

    float* by1 = boxbuf;
    float* bx1 = boxbuf + 448;
    float* by2 = boxbuf + 896;
    float* bx2 = boxbuf + 1344;
    float* bar = boxbuf + 1792;

    const int tid = threadIdx.x;
    const int wv = tid >> 6;
    const int lane = tid & 63;
    const int b = blockIdx.x & 7;     // all 80 class-blocks of an image on one XCD
    const int c = blockIdx.x >> 3;

    const u16* keys16g = scores16 + (long)(b * NCLS + c) * N_TOT;
    const uint4* k4g = (const uint4*)keys16g;
    const uint4* k4 = (const uint4*)skey;       // LDS view, 8 u16 per uint4
    const int N8 = N_TOT >> 3;                  // 2016

    // ---- Phase A: stage to LDS + pass-1 histogram (hi byte, wave-aggregated)
    if (tid < 260) hist[tid] = 0u;
    if (tid == 0) sh_gcnt = 0;
    __syncthreads();
#pragma unroll
    for (int it = 0; it < 4; ++it) {
        int i4 = tid + it * NTHR;
        bool v = i4 < N8;
        u32 e0 = 0, e1 = 0, e2 = 0, e3 = 0, e4 = 0, e5 = 0, e6 = 0, e7 = 0;
        if (v) {
            uint4 kk = k4g[i4];
            ((uint4*)skey)[i4] = kk;
            e0 = kk.x & 0xffffu; e1 = kk.x >> 16; e2 = kk.y & 0xffffu; e3 = kk.y >> 16;
            e4 = kk.z & 0xffffu; e5 = kk.z >> 16; e6 = kk.w & 0xffffu; e7 = kk.w >> 16;
        }
        hist_agg(hist, e0 >> 8, v, lane); hist_agg(hist, e1 >> 8, v, lane);
        hist_agg(hist, e2 >> 8, v, lane); hist_agg(hist, e3 >> 8, v, lane);
        hist_agg(hist, e4 >> 8, v, lane); hist_agg(hist, e5 >> 8, v, lane);
        hist_agg(hist, e6 >> 8, v, lane); hist_agg(hist, e7 >> 8, v, lane);
    }
    __syncthreads();

    int need = PRE_K;
    digit_select(hist, need, &sh_dg, &sh_S1, &sh_T, tid);
    u32 thr = sh_dg; need -= (int)sh_S1;
    int C = (PRE_K - need) + (int)sh_T;
    int lvl = 1;

    // ---- pass 2: low byte among hi==thr (spread -> direct atomics), LDS scan
    if (C > CAP) {
        if (tid < 256) hist[tid] = 0u;
        __syncthreads();
#pragma unroll
        for (int it = 0; it < 4; ++it) {
            int i4 = tid + it * NTHR;
            if (i4 < N8) {
                uint4 kk = k4[i4];
                u32 e[8] = { kk.x & 0xffffu, kk.x >> 16, kk.y & 0xffffu, kk.y >> 16,
                             kk.z & 0xffffu, kk.z >> 16, kk.w & 0xffffu, kk.w >> 16 };
#pragma unroll
                for (int q = 0; q < 8; ++q)
                    if ((e[q] >> 8) == thr) atomicAdd(&hist[e[q] & 255u], 1u);
            }
        }
        __syncthreads();
        digit_select(hist, need, &sh_dg, &sh_S1, &sh_T, tid);
        thr = (thr << 8) | sh_dg; need -= (int)sh_S1;
        C = (PRE_K - need) + (int)sh_T;
        lvl = 2;
    }

    // ---- pass 3 (rare): refine with recomputed f32 bits [15:8]
    if (C > CAP) {
        u32 t16 = thr;
        if (tid < 256) hist[tid] = 0u;
        __syncthreads();
        for (int i = tid; i < N_TOT; i += NTHR) {
            if (skey[i] == (u16)t16) {
                u32 kb = __float_as_uint(score_f32(i, b, c, p3, p4, p5));
                atomicAdd(&hist[(kb >> 8) & 255u], 1u);
            }
        }
        __syncthreads();
        digit_select(hist, need, &sh_dg, &sh_S1, &sh_T, tid);
        thr = (thr << 8) | sh_dg; need -= (int)sh_S1;
        C = (PRE_K - need) + (int)sh_T;
        lvl = 3;
    }

    // ---- pass 4 (rare): full 32-bit
    if (C > CAP) {
        u32 t16 = thr >> 8;
        if (tid < 256) hist[tid] = 0u;
        __syncthreads();
        for (int i = tid; i < N_TOT; i += NTHR) {
            if (skey[i] == (u16)t16) {
                u32 kb = __float_as_uint(score_f32(i, b, c, p3, p4, p5));
                if ((kb >> 8) == thr) atomicAdd(&hist[kb & 255u], 1u);
            }
        }
        __syncthreads();
        digit_select(hist, need, &sh_dg, &sh_S1, &sh_T, tid);
        thr = (thr << 8) | sh_dg; need -= (int)sh_S1;
        C = (PRE_K - need) + (int)sh_T;
        lvl = 4;
    }

    // ---- collect candidates (superset ok; sort trims exactly)
    if (lvl <= 2) {
#pragma unroll
        for (int it = 0; it < 4; ++it) {
            int i4 = tid + it * NTHR;
            if (i4 < N8) {
                uint4 kk = k4[i4];
                int i0 = i4 << 3;
                u32 e[8] = { kk.x & 0xffffu, kk.x >> 16, kk.y & 0xffffu, kk.y >> 16,
                             kk.z & 0xffffu, kk.z >> 16, kk.w & 0xffffu, kk.w >> 16 };
#pragma unroll
                for (int q = 0; q < 8; ++q) {
                    bool take = (lvl == 1) ? ((e[q] >> 8) >= thr) : (e[q] >= thr);
                    if (take) {
                        int p = atomicAdd(&sh_gcnt, 1);
                        int i = i0 + q;
                        u32 kb = __float_as_uint(score_f32(i, b, c, p3, p4, p5));
                        cand[p] = ((u64)kb << 32) | (u32)(0xFFFFFFFFu - (u32)i);
                    }
                }
            }
        }
        __syncthreads();
        for (int t = C + tid; t < CAP; t += NTHR) cand[t] = 0ull;
    } else if (C <= CAP) {
        u32 t16 = (lvl == 3) ? (thr >> 8) : (thr >> 16);
        for (int i = tid; i < N_TOT; i += NTHR) {
            u32 k = skey[i];
            bool take = false;
            u32 kb = 0;
            if (k > t16) { take = true; kb = __float_as_uint(score_f32(i, b, c, p3, p4, p5)); }
            else if (k == t16) {
                kb = __float_as_uint(score_f32(i, b, c, p3, p4, p5));
                take = (lvl == 3) ? ((kb >> 8) >= thr) : (kb >= thr);
            }
            if (take) {
                int p = atomicAdd(&sh_gcnt, 1);
                cand[p] = ((u64)kb << 32) | (u32)(0xFFFFFFFFu - (u32)i);
            }
        }
        __syncthreads();
        for (int t = C + tid; t < CAP; t += NTHR) cand[t] = 0ull;
    } else {
        // lvl==4 and >CAP ties at one exact f32 value: index-rank trim
        u32 t16 = thr >> 16;
        for (int i = tid; i < N_TOT; i += NTHR) {
            u32 k = skey[i];
            if (k < t16) continue;
            u32 kb = __float_as_uint(score_f32(i, b, c, p3, p4, p5));
            if (kb > thr) {
                int p = atomicAdd(&sh_gcnt, 1);
                cand[p] = ((u64)kb << 32) | (u32)(0xFFFFFFFFu - (u32)i);
            }
        }
        __syncthreads();
        const int G = sh_gcnt;   // == PRE_K - need
        u32* scr = (u32*)boxbuf; // boxes not gathered yet
        int lo = tid * 32; if (lo > N_TOT) lo = N_TOT;
        int hi = lo + 32;  if (hi > N_TOT) hi = N_TOT;
        int lc = 0;
        for (int i = lo; i < hi; ++i)
            if (skey[i] == (u16)t16 &&
                __float_as_uint(score_f32(i, b, c, p3, p4, p5)) == thr) ++lc;
        u32* sc_cur = scr; u32* sc_oth = scr + 512;
        sc_cur[tid] = (u32)lc;
        __syncthreads();
        for (int off = 1; off < NTHR; off <<= 1) {
            sc_oth[tid] = sc_cur[tid] + ((tid >= off) ? sc_cur[tid - off] : 0u);
            __syncthreads();
            u32* tmp = sc_cur; sc_cur = sc_oth; sc_oth = tmp;
        }
        int r = (int)sc_cur[tid] - lc;
        for (int i = lo; i < hi; ++i) {
            if (skey[i] == (u16)t16 &&
                __float_as_uint(score_f32(i, b, c, p3, p4, p5)) == thr) {
                if (r < need) cand[G + r] = ((u64)thr << 32) | (u32)(0xFFFFFFFFu - (u32)i);
                ++r;
            }
        }
        __syncthreads();
        for (int t = PRE_K + tid; t < CAP; t += NTHR) cand[t] = 0ull;
    }
    __syncthreads();

    sort512(cand, tid);

    // ---- gather top-400 boxes (SoA, padded to 448)
    const float4* btab = (const float4*)boxes;
    for (int t = tid; t < 448; t += NTHR) {
        float y1 = 0.f, x1 = 0.f, y2 = 0.f, x2 = 0.f;
        if (t < PRE_K) {
            u64 key = cand[t];
            if ((key >> 32) != 0ull) {
                int idx = (int)(0xFFFFFFFFu - (u32)(key & 0xFFFFFFFFull));
                float4 bb = btab[b * N_TOT + idx];
                y1 = bb.x; x1 = bb.y; y2 = bb.z; x2 = bb.w;
            }
        }
        by1[t] = y1; bx1[t] = x1; by2[t] = y2; bx2[t] = x2;
        bar[t] = (y2 - y1) * (x2 - x1);
    }
    if (tid < 16) keepb[tid] = (tid < 12) ? 0xFFFFFFFFu : ((tid == 12) ? 0xFFFFu : 0u);
    __syncthreads();

    // ---- blocked NMS: per 64-row chunk {parallel diag build, register-serial
    //      diagonal greedy, parallel apply to later columns}
    for (int ch = 0; ch < 7; ++ch) {
        const int rbase = ch << 6;
        // row boxes for this chunk in regs (lane <-> row rbase+lane)
        const float ry1 = by1[rbase + lane], rx1v = bx1[rbase + lane];
        const float ry2 = by2[rbase + lane], rx2v = bx2[rbase + lane];
        const float ra  = bar[rbase + lane];

        // (1) diagonal block build: wave wv builds columns jl = wv*8+q
#pragma unroll
        for (int q = 0; q < 8; ++q) {
            const int jl = wv * 8 + q;
            const int jj = rbase + jl;
            u64 m = 0ull;
            if (jj < PRE_K && ((keepb[jj >> 5] >> (jj & 31)) & 1u)) {
                float cy1 = by1[jj], cx1 = bx1[jj], cy2 = by2[jj], cx2 = bx2[jj], ca = bar[jj];
                float ty = fmaxf(ry1, cy1), tx = fmaxf(rx1v, cx1);
                float byv = fminf(ry2, cy2), rxv = fminf(rx2v, cx2);
                float inter = fmaxf(byv - ty, 0.f) * fmaxf(rxv - tx, 0.f);
                float uni = ra + ca - inter;
                bool o = (lane < jl) && ((inter / fmaxf(uni, 1e-9f)) > NMS_T);
                m = __ballot(o);
            }
            if (lane == 0) diagbuf[jl] = m;
        }
        __syncthreads();

        // (2) serial diagonal greedy: wave 0, registers only
        if (tid < 64) {
            u64 dg = diagbuf[lane];
            int ri = rbase + lane;
            int alive = (ri < PRE_K) ? (int)((keepb[ri >> 5] >> (ri & 31)) & 1u) : 0;
            u64 M = __ballot(alive != 0);
            for (int i = 0; i < 64; ++i) {
                if ((M >> i) & 1ull) {
                    int kill = (int)((dg >> i) & 1ull);
                    alive &= ~kill;
                    M = __ballot(alive != 0);
                }
            }
            if (lane == 0) {
                sh_keptM = M;
                keepb[2 * ch]     = (u32)(M & 0xFFFFFFFFull);
                keepb[2 * ch + 1] = (u32)(M >> 32);
            }
        }
        __syncthreads();

        // (3) parallel apply to later columns
        {
            const u64 keptM = sh_keptM;
            if (keptM != 0ull) {
                for (int jj = rbase + 64 + wv; jj < PRE_K; jj += 8) {
                    if ((keepb[jj >> 5] >> (jj & 31)) & 1u) {
                        float cy1 = by1[jj], cx1 = bx1[jj], cy2 = by2[jj], cx2 = bx2[jj], ca = bar[jj];
                        float ty = fmaxf(ry1, cy1), tx = fmaxf(rx1v, cx1);
                        float byv = fminf(ry2, cy2), rxv = fminf(rx2v, cx2);
                        float inter = fmaxf(byv - ty, 0.f) * fmaxf(rxv - tx, 0.f);
                        float uni = ra + ca - inter;
                        bool o = (inter / fmaxf(uni, 1e-9f)) > NMS_T;
                        u64 m = __ballot(o);
                        if ((m & keptM) != 0ull && lane == 0)
                            atomicAnd(&keepb[jj >> 5], ~(1u << (jj & 31)));
                    }
                }
            }
        }
        __syncthreads();
    }

    if (tid == 0) {
        int acc = 0;
        for (int w = 0; w < 14; ++w) { wpre14[w] = acc; acc += __popc(keepb[w]); }
        sh_ncnt = acc < KEEP_CAP ? acc : KEEP_CAP;
    }
    __syncthreads();

    // ---- compact kept (rank via popcount), cap 200, zero-pad
    const int blk_out = b * NCLS + c;
    float* osc = ksc + (long)blk_out * KEEP_CAP;
    float* obx = kbox + (long)blk_out * KEEP_CAP * 4;
    for (int t = tid; t < PRE_K; t += NTHR) {
        u32 kw = keepb[t >> 5];
        if ((kw >> (t & 31)) & 1u) {
            int pos = wpre14[t >> 5] + __popc(kw & ((1u << (t & 31)) - 1u));
            if (pos < KEEP_CAP) {
                osc[pos] = __uint_as_float((u32)(cand[t] >> 32));
                obx[pos * 4 + 0] = by1[t]; obx[pos * 4 + 1] = bx1[t];
                obx[pos * 4 + 2] = by2[t]; obx[pos * 4 + 3] = bx2[t];
            }
        }
    }
    for (int t = sh_ncnt + tid; t < KEEP_CAP; t += NTHR) {
        osc[t] = 0.0f;
        obx[t * 4 + 0] = 0.f; obx[t * 4 + 1] = 0.f;
        obx[t * 4 + 2] = 0.f; obx[t * 4 + 3] = 0.f;
    }
}

// ---- f32-key radix top-K (used by final_topk over compacted scores)
__device__ __forceinline__ void radix_topk_sort_f32(
    const u32* __restrict__ keys, int n, int K,
    u64* cand, u32* hist, u32* scr,
    u32* sh_dg, u32* sh_S1, u32* sh_T, int* sh_gcnt, int tid)
{
    int need = K;
    digit_select(hist, need, sh_dg, sh_S1, sh_T, tid);
    u32 thr = *sh_dg; need -= (int)*sh_S1;
    int C = (K - need) + (int)*sh_T;
    int eshift = 24;

    const uint4* k4 = (const uint4*)keys;
    const int n4 = n >> 2;
    const int nIter = (n4 + NTHR - 1) / NTHR;

    for (int shift = 16; shift >= 0 && C > CAP; shift -= 8) {
        if (tid < 256) hist[tid] = 0u;
        __syncthreads();
        for (int it = 0; it < nIter; ++it) {
            int i4 = tid + it * NTHR;
            if (i4 < n4) {
                uint4 kk = k4[i4];
                if ((kk.x >> (shift + 8)) == thr) atomicAdd(&hist[(kk.x >> shift) & 255u], 1u);
                if ((kk.y >> (shift + 8)) == thr) atomicAdd(&hist[(kk.y >> shift) & 255u], 1u);
                if ((kk.z >> (shift + 8)) == thr) atomicAdd(&hist[(kk.z >> shift) & 255u], 1u);
                if ((kk.w >> (shift + 8)) == thr) atomicAdd(&hist[(kk.w >> shift) & 255u], 1u);
            }
        }
        __syncthreads();
        digit_select(hist, need, sh_dg, sh_S1, sh_T, tid);
        thr = (thr << 8) | *sh_dg; need -= (int)*sh_S1;
        C = (K - need) + (int)*sh_T;
        eshift = shift;
    }

    if (C <= CAP) {
        for (int it = 0; it < nIter; ++it) {
            int i4 = tid + it * NTHR;
            if (i4 < n4) {
                uint4 kk = k4[i4];
                int i0 = i4 << 2;
                if ((kk.x >> eshift) >= thr) { int p = atomicAdd(sh_gcnt, 1); cand[p] = ((u64)kk.x << 32) | (u32)(0xFFFFFFFFu - (u32)(i0 + 0)); }
                if ((kk.y >> eshift) >= thr) { int p = atomicAdd(sh_gcnt, 1); cand[p] = ((u64)kk.y << 32) | (u32)(0xFFFFFFFFu - (u32)(i0 + 1)); }
                if ((kk.z >> eshift) >= thr) { int p = atomicAdd(sh_gcnt, 1); cand[p] = ((u64)kk.z << 32) | (u32)(0xFFFFFFFFu - (u32)(i0 + 2)); }
                if ((kk.w >> eshift) >= thr) { int p = atomicAdd(sh_gcnt, 1); cand[p] = ((u64)kk.w << 32) | (u32)(0xFFFFFFFFu - (u32)(i0 + 3)); }
            }
        }
        __syncthreads();
        for (int t = C + tid; t < CAP; t += NTHR) cand[t] = 0ull;
    } else {
        for (int i = tid; i < n; i += NTHR) {
            u32 k = keys[i];
            if (k > thr) {
                int p = atomicAdd(sh_gcnt, 1);
                cand[p] = ((u64)k << 32) | (u32)(0xFFFFFFFFu - (u32)i);
            }
        }
        __syncthreads();
        const int G = *sh_gcnt;
        int lo = tid * 32; if (lo > n) lo = n;
        int hi = lo + 32;  if (hi > n) hi = n;
        int lc = 0;
        for (int i = lo; i < hi; ++i) if (keys[i] == thr) ++lc;
        u32* sc_cur = scr; u32* sc_oth = scr + 512;
        sc_cur[tid] = (u32)lc;
        __syncthreads();
        for (int off = 1; off < NTHR; off <<= 1) {
            sc_oth[tid] = sc_cur[tid] + ((tid >= off) ? sc_cur[tid - off] : 0u);
            __syncthreads();
            u32* tmp = sc_cur; sc_cur = sc_oth; sc_oth = tmp;
        }
        int r = (int)sc_cur[tid] - lc;
        for (int i = lo; i < hi; ++i) {
            if (keys[i] == thr) {
                if (r < need) cand[G + r] = ((u64)thr << 32) | (u32)(0xFFFFFFFFu - (u32)i);
                ++r;
            }
        }
        __syncthreads();
        for (int t = K + tid; t < CAP; t += NTHR) cand[t] = 0ull;
    }
    __syncthreads();
    sort512(cand, tid);
}

// ---- Stage 3: per image top-200 over 16000 compacted candidates -> outputs
__global__ __launch_bounds__(NTHR) void final_topk_kernel(
    const float* __restrict__ ksc, const float* __restrict__ kbox,
    float* __restrict__ out)
{
    __shared__ alignas(16) u64 cand[CAP];
    __shared__ u32 hist[260];
    __shared__ u32 scr[1024];
    __shared__ u32 sh_dg, sh_S1, sh_T;
    __shared__ int sh_gcnt;

    const int tid = threadIdx.x;
    const int lane = tid & 63;
    const int b = blockIdx.x;
    const u32* keys = (const u32*)(ksc + (long)b * M_FIN);

    if (tid < 260) hist[tid] = 0u;
    if (tid == 0) sh_gcnt = 0;
    __syncthreads();
    const uint4* k4 = (const uint4*)keys;
#pragma unroll
    for (int it = 0; it < 8; ++it) {
        int i4 = tid + it * NTHR;
        bool v = i4 < (M_FIN >> 2);
        u32 d0 = 0, d1 = 0, d2 = 0, d3 = 0;
        if (v) {
            uint4 kk = k4[i4];
            d0 = kk.x >> 24; d1 = kk.y >> 24; d2 = kk.z >> 24; d3 = kk.w >> 24;
        }
        hist_agg(hist, d0, v, lane);
        hist_agg(hist, d1, v, lane);
        hist_agg(hist, d2, v, lane);
        hist_agg(hist, d3, v, lane);
    }
    __syncthreads();

    radix_topk_sort_f32(keys, M_FIN, MAX_BOXES, cand, hist, scr,
                        &sh_dg, &sh_S1, &sh_T, &sh_gcnt, tid);

    float* obb = out;                         // (8,200,4)
    float* ocf = out + 8 * MAX_BOXES * 4;     // (8,200)
    float* ocl = ocf + 8 * MAX_BOXES;         // (8,200)
    float* onm = ocl + 8 * MAX_BOXES;         // (8,)

    float s = 0.f;
    if (tid < MAX_BOXES) {
        u64 key = cand[tid];
        s = __uint_as_float((u32)(key >> 32));
        float y1 = 0.f, x1 = 0.f, y2 = 0.f, x2 = 0.f, cid = 0.f;
        if (s > 0.0f) {
            int i = (int)(0xFFFFFFFFu - (u32)(key & 0xFFFFFFFFull));
            int cc = i / KEEP_CAP, j = i % KEEP_CAP;
            const float* bb = kbox + (((long)b * NCLS + cc) * KEEP_CAP + j) * 4;
            y1 = bb[0]; x1 = bb[1]; y2 = bb[2]; x2 = bb[3];
            cid = (float)cc;
        }
        long o = (long)b * MAX_BOXES + tid;
        obb[o * 4 + 0] = y1; obb[o * 4 + 1] = x1; obb[o * 4 + 2] = y2; obb[o * 4 + 3] = x2;
        ocf[o] = s; ocl[o] = cid;
    }
    int cnt = __syncthreads_count(tid < MAX_BOXES && s > 0.0f);
    if (tid == 0) onm[b] = (float)cnt;
}

extern "C" void kernel_launch(void* const* d_in, const int* in_sizes, int n_in,
                              void* d_out, int out_size, void* d_ws, size_t ws_size,
                              hipStream_t stream) {
    const float* p3 = (const float*)d_in[0];
    const float* p4 = (const float*)d_in[1];
    const float* p5 = (const float*)d_in[2];
    const float* a3 = (const float*)d_in[3];
    const float* a4 = (const float*)d_in[4];
    const float* a5 = (const float*)d_in[5];
    float* out = (float*)d_out;

    const size_t s16_bytes  = (size_t)8 * NCLS * N_TOT * 2;      // 20,643,840
    const size_t box_bytes  = (size_t)8 * N_TOT * 16;            //  2,064,384
    const size_t ksc_bytes  = (size_t)8 * NCLS * KEEP_CAP * 4;   //    512,000

    u16*   scores16 = (u16*)d_ws;
    float* boxes    = (float*)((char*)d_ws + s16_bytes);
    float* ksc      = (float*)((char*)d_ws + s16_bytes + box_bytes);
    float* kbox     = (float*)((char*)d_ws + s16_bytes + box_bytes + ksc_bytes);

    decode_kernel<<<504, 256, 0, stream>>>(p3, p4, p5, a3, a4, a5, scores16, boxes);
    topk_nms_fused<<<8 * NCLS, NTHR, 0, stream>>>(scores16, boxes, p3, p4, p5, ksc, kbox);
    final_topk_kernel<<<8, NTHR, 0, stream>>>(ksc, kbox, out);
}

// Round 8
// 168.941 us; speedup vs baseline: 1.2070x; 1.0030x over previous
//
#include <hip/hip_runtime.h>
#include <math.h>

#define NCLS 80
#define PRE_K 400
#define MAX_BOXES 200
#define KEEP_CAP 200
#define N_TOT 16128
#define M_FIN (NCLS * KEEP_CAP)   // 16000
#define NMS_T 0.6f
#define NTHR 512
#define CAP 512                    // candidate buffer (>= K + tie margin)

typedef unsigned long long u64;
typedef unsigned int u32;
typedef unsigned short u16;

__device__ __forceinline__ float sigf(float x) { return 1.0f / (1.0f + expf(-x)); }

// exact score recompute — bitwise-identical expression to decode_kernel's store
__device__ __forceinline__ float score_f32(int idx, int b, int c,
    const float* __restrict__ p3, const float* __restrict__ p4, const float* __restrict__ p5)
{
    const float* base; int W, n;
    if (idx < 12288)      { base = p3; W = 64; n = idx; }
    else if (idx < 15360) { base = p4; W = 32; n = idx - 12288; }
    else                  { base = p5; W = 16; n = idx - 15360; }
    int a = n % 3, hw = n / 3, w = hw % W, h = hw / W;
    const float* rec = base + (((b * W + h) * W + w) * 255 + a * 85);
    return sigf(rec[5 + c]) * sigf(rec[4]);
}

// wave-aggregated LDS histogram add: one atomic per distinct digit per wave
__device__ __forceinline__ void hist_agg(u32* hist, u32 d, bool valid, int lane)
{
    u64 act = __ballot(valid);
    while (act) {
        int ldr = __ffsll((unsigned long long)act) - 1;
        u32 dl = __shfl(d, ldr, 64);
        u64 m = __ballot(valid && d == dl);
        if (lane == ldr) atomicAdd(&hist[dl], (u32)__popcll(m));
        act &= ~m;
    }
}

// hist[256] -> digit d with S_d >= need > S_{d+1}; wave 0 only, 1 barrier.
__device__ __forceinline__ void digit_select(const u32* hist, int need,
                                             u32* sh_dg, u32* sh_S1, u32* sh_T, int tid)
{
    if (tid < 64) {
        const int lane = tid;
        u32 h0 = hist[4 * lane + 0], h1 = hist[4 * lane + 1];
        u32 h2 = hist[4 * lane + 2], h3 = hist[4 * lane + 3];
        u32 loc = h0 + h1 + h2 + h3;
        u32 s = loc;
#pragma unroll
        for (int off = 1; off < 64; off <<= 1) {
            u32 t = __shfl_down(s, off, 64);
            if (lane + off < 64) s += t;
        }
        u32 after = s - loc;
        u32 S3 = h3 + after, S2 = h2 + S3, S1v = h1 + S2, S0 = h0 + S1v;
        u32 Sarr[5] = { S0, S1v, S2, S3, after };
#pragma unroll
        for (int k = 0; k < 4; ++k) {
            if ((int)Sarr[k] >= need && need > (int)Sarr[k + 1]) {
                *sh_dg = (u32)(4 * lane + k);
                *sh_S1 = Sarr[k + 1];
                *sh_T  = Sarr[k] - Sarr[k + 1];
            }
        }
    }
    __syncthreads();
}

// bitonic sort CAP=512 desc over LDS cand, one elem/thread; k<=64 stages in-wave
__device__ __forceinline__ void sort512(u64* cand, int tid)
{
    u64 v = cand[tid];
#pragma unroll
    for (int k2 = 2; k2 <= 64; k2 <<= 1) {
#pragma unroll
        for (int j = k2 >> 1; j > 0; j >>= 1) {
            u64 p = __shfl_xor(v, j, 64);
            bool takeMax = ((tid & k2) == 0) ^ ((tid & j) != 0);
            v = takeMax ? (v >= p ? v : p) : (v <= p ? v : p);
        }
    }
    for (int k2 = 128; k2 <= CAP; k2 <<= 1) {
        for (int j = k2 >> 1; j >= 64; j >>= 1) {
            __syncthreads();
            cand[tid] = v;
            __syncthreads();
            u64 p = cand[tid ^ j];
            bool takeMax = ((tid & k2) == 0) ^ ((tid & j) != 0);
            v = takeMax ? (v >= p ? v : p) : (v <= p ? v : p);
        }
#pragma unroll
        for (int j = 32; j > 0; j >>= 1) {
            u64 p = __shfl_xor(v, j, 64);
            bool takeMax = ((tid & k2) == 0) ^ ((tid & j) != 0);
            v = takeMax ? (v >= p ? v : p) : (v <= p ? v : p);
        }
    }
    __syncthreads();
    cand[tid] = v;
    __syncthreads();
}

// ---- Stage 1: decode u16 score keys [b][c][n] + clipped boxes float4[b][n]
__global__ __launch_bounds__(256) void decode_kernel(
    const float* __restrict__ p3, const float* __restrict__ p4, const float* __restrict__ p5,
    const float* __restrict__ a3, const float* __restrict__ a4, const float* __restrict__ a5,
    u16* __restrict__ scores16, float* __restrict__ boxes)
{
    const int blk = blockIdx.x;
    const int b = blk & 7;
    const int n = ((blk >> 3) << 8) + threadIdx.x;

    const float* base; const float* anc; int logw, nn; float sx;
    if (n < 12288)      { base = p3; anc = a3; logw = 6; nn = n;         sx = 1.2f;  }
    else if (n < 15360) { base = p4; anc = a4; logw = 5; nn = n - 12288; sx = 1.1f;  }
    else                { base = p5; anc = a5; logw = 4; nn = n - 15360; sx = 1.05f; }
    const int W = 1 << logw;
    const int a = nn % 3; const int hw = nn / 3;
    const int w = hw & (W - 1); const int h = hw >> logw;
    const float winv = 1.0f / (float)W;
    const float* rec = base + ((size_t)((b * W + h) * W + w) * 255 + a * 85);

    float tx = rec[0], ty = rec[1], tw = rec[2], th = rec[3], to = rec[4];
    float sobj = sigf(to);
    float cx = (sigf(tx) * sx - 0.5f * (sx - 1.0f) + (float)w) * winv;
    float cy = (sigf(ty) * sx - 0.5f * (sx - 1.0f) + (float)h) * winv;
    float bw = expf(tw) * anc[a * 2 + 0] * (1.0f / 512.0f);   // W*stride == 512 all levels
    float bh = expf(th) * anc[a * 2 + 1] * (1.0f / 512.0f);
    float x1 = cx - 0.5f * bw, x2 = cx + 0.5f * bw;
    float y1 = cy - 0.5f * bh, y2 = cy + 0.5f * bh;
    y1 = fminf(fmaxf(y1, 0.f), 1.f); x1 = fminf(fmaxf(x1, 0.f), 1.f);
    y2 = fminf(fmaxf(y2, 0.f), 1.f); x2 = fminf(fmaxf(x2, 0.f), 1.f);
    float4 bb; bb.x = y1; bb.y = x1; bb.z = y2; bb.w = x2;
    ((float4*)boxes)[b * N_TOT + n] = bb;

    u16* sb = scores16 + (long)b * NCLS * N_TOT + n;
#pragma unroll 8
    for (int cc = 0; cc < NCLS; ++cc)
        sb[(long)cc * N_TOT] = (u16)(__float_as_uint(sigf(rec[5 + cc]) * sobj) >> 16);
}

// ---- Stage 2: per (image,class) u16-radix top-400 -> sort -> blocked NMS
__global__ __launch_bounds__(NTHR, 4) void topk_nms_fused(
    const u16* __restrict__ scores16, const float* __restrict__ boxes,
    const float* __restrict__ p3, const float* __restrict__ p4, const float* __restrict__ p5,
    float* __restrict__ ksc, float* __restrict__ kbox)
{
    __shared__ alignas(16) u16 skey[N_TOT];          // 32256 B staged keys
    __shared__ alignas(16) u64 cand[CAP];            // 4096 B
    __shared__ u32 hist[260];                        // 1040 B
    __shared__ u32 sh_dg, sh_S1, sh_T;
    __shared__ int sh_gcnt;
    __shared__ alignas(16) float boxbuf[5 * 448];    // 8960 B (also lvl-4 trim scratch)
    __shared__ alignas(16) u64 diagbuf[64];          // 512 B
    __shared__ u32 keepb[16];                        // 448 keep bits (14 words used)
    __shared__ u64 sh_keptM;
    __shared__ int wpre14[14];
    __shared__ int sh_ncnt;

    float* by1 = boxbuf;
    float* bx1 = boxbuf + 448;
    float* by2 = boxbuf + 896;
    float* bx2 = boxbuf + 1344;
    float* bar = boxbuf + 1792;

    const int tid = threadIdx.x;
    const int wv = tid >> 6;
    const int lane = tid & 63;
    const int b = blockIdx.x & 7;     // all 80 class-blocks of an image on one XCD
    const int c = blockIdx.x >> 3;

    const u16* keys16g = scores16 + (long)(b * NCLS + c) * N_TOT;
    const uint4* k4g = (const uint4*)keys16g;
    const uint4* k4 = (const uint4*)skey;       // LDS view, 8 u16 per uint4
    const int N8 = N_TOT >> 3;                  // 2016

    // ---- Phase A: stage to LDS + pass-1 histogram (hi byte, wave-aggregated)
    if (tid < 260) hist[tid] = 0u;
    if (tid == 0) sh_gcnt = 0;
    __syncthreads();
#pragma unroll
    for (int it = 0; it < 4; ++it) {
        int i4 = tid + it * NTHR;
        bool v = i4 < N8;
        u32 e0 = 0, e1 = 0, e2 = 0, e3 = 0, e4 = 0, e5 = 0, e6 = 0, e7 = 0;
        if (v) {
            uint4 kk = k4g[i4];
            ((uint4*)skey)[i4] = kk;
            e0 = kk.x & 0xffffu; e1 = kk.x >> 16; e2 = kk.y & 0xffffu; e3 = kk.y >> 16;
            e4 = kk.z & 0xffffu; e5 = kk.z >> 16; e6 = kk.w & 0xffffu; e7 = kk.w >> 16;
        }
        hist_agg(hist, e0 >> 8, v, lane); hist_agg(hist, e1 >> 8, v, lane);
        hist_agg(hist, e2 >> 8, v, lane); hist_agg(hist, e3 >> 8, v, lane);
        hist_agg(hist, e4 >> 8, v, lane); hist_agg(hist, e5 >> 8, v, lane);
        hist_agg(hist, e6 >> 8, v, lane); hist_agg(hist, e7 >> 8, v, lane);
    }
    __syncthreads();

    int need = PRE_K;
    digit_select(hist, need, &sh_dg, &sh_S1, &sh_T, tid);
    u32 thr = sh_dg; need -= (int)sh_S1;
    int C = (PRE_K - need) + (int)sh_T;
    int lvl = 1;

    // ---- pass 2: low byte among hi==thr (spread -> direct atomics), LDS scan
    if (C > CAP) {
        if (tid < 256) hist[tid] = 0u;
        __syncthreads();
#pragma unroll
        for (int it = 0; it < 4; ++it) {
            int i4 = tid + it * NTHR;
            if (i4 < N8) {
                uint4 kk = k4[i4];
                u32 e[8] = { kk.x & 0xffffu, kk.x >> 16, kk.y & 0xffffu, kk.y >> 16,
                             kk.z & 0xffffu, kk.z >> 16, kk.w & 0xffffu, kk.w >> 16 };
#pragma unroll
                for (int q = 0; q < 8; ++q)
                    if ((e[q] >> 8) == thr) atomicAdd(&hist[e[q] & 255u], 1u);
            }
        }
        __syncthreads();
        digit_select(hist, need, &sh_dg, &sh_S1, &sh_T, tid);
        thr = (thr << 8) | sh_dg; need -= (int)sh_S1;
        C = (PRE_K - need) + (int)sh_T;
        lvl = 2;
    }

    // ---- pass 3 (rare): refine with recomputed f32 bits [15:8]
    if (C > CAP) {
        u32 t16 = thr;
        if (tid < 256) hist[tid] = 0u;
        __syncthreads();
        for (int i = tid; i < N_TOT; i += NTHR) {
            if (skey[i] == (u16)t16) {
                u32 kb = __float_as_uint(score_f32(i, b, c, p3, p4, p5));
                atomicAdd(&hist[(kb >> 8) & 255u], 1u);
            }
        }
        __syncthreads();
        digit_select(hist, need, &sh_dg, &sh_S1, &sh_T, tid);
        thr = (thr << 8) | sh_dg; need -= (int)sh_S1;
        C = (PRE_K - need) + (int)sh_T;
        lvl = 3;
    }

    // ---- pass 4 (rare): full 32-bit
    if (C > CAP) {
        u32 t16 = thr >> 8;
        if (tid < 256) hist[tid] = 0u;
        __syncthreads();
        for (int i = tid; i < N_TOT; i += NTHR) {
            if (skey[i] == (u16)t16) {
                u32 kb = __float_as_uint(score_f32(i, b, c, p3, p4, p5));
                if ((kb >> 8) == thr) atomicAdd(&hist[kb & 255u], 1u);
            }
        }
        __syncthreads();
        digit_select(hist, need, &sh_dg, &sh_S1, &sh_T, tid);
        thr = (thr << 8) | sh_dg; need -= (int)sh_S1;
        C = (PRE_K - need) + (int)sh_T;
        lvl = 4;
    }

    // ---- collect candidates (superset ok; sort trims exactly)
    if (lvl <= 2) {
#pragma unroll
        for (int it = 0; it < 4; ++it) {
            int i4 = tid + it * NTHR;
            if (i4 < N8) {
                uint4 kk = k4[i4];
                int i0 = i4 << 3;
                u32 e[8] = { kk.x & 0xffffu, kk.x >> 16, kk.y & 0xffffu, kk.y >> 16,
                             kk.z & 0xffffu, kk.z >> 16, kk.w & 0xffffu, kk.w >> 16 };
#pragma unroll
                for (int q = 0; q < 8; ++q) {
                    bool take = (lvl == 1) ? ((e[q] >> 8) >= thr) : (e[q] >= thr);
                    if (take) {
                        int p = atomicAdd(&sh_gcnt, 1);
                        int i = i0 + q;
                        u32 kb = __float_as_uint(score_f32(i, b, c, p3, p4, p5));
                        cand[p] = ((u64)kb << 32) | (u32)(0xFFFFFFFFu - (u32)i);
                    }
                }
            }
        }
        __syncthreads();
        for (int t = C + tid; t < CAP; t += NTHR) cand[t] = 0ull;
    } else if (C <= CAP) {
        u32 t16 = (lvl == 3) ? (thr >> 8) : (thr >> 16);
        for (int i = tid; i < N_TOT; i += NTHR) {
            u32 k = skey[i];
            bool take = false;
            u32 kb = 0;
            if (k > t16) { take = true; kb = __float_as_uint(score_f32(i, b, c, p3, p4, p5)); }
            else if (k == t16) {
                kb = __float_as_uint(score_f32(i, b, c, p3, p4, p5));
                take = (lvl == 3) ? ((kb >> 8) >= thr) : (kb >= thr);
            }
            if (take) {
                int p = atomicAdd(&sh_gcnt, 1);
                cand[p] = ((u64)kb << 32) | (u32)(0xFFFFFFFFu - (u32)i);
            }
        }
        __syncthreads();
        for (int t = C + tid; t < CAP; t += NTHR) cand[t] = 0ull;
    } else {
        // lvl==4 and >CAP ties at one exact f32 value: index-rank trim
        u32 t16 = thr >> 16;
        for (int i = tid; i < N_TOT; i += NTHR) {
            u32 k = skey[i];
            if (k < t16) continue;
            u32 kb = __float_as_uint(score_f32(i, b, c, p3, p4, p5));
            if (kb > thr) {
                int p = atomicAdd(&sh_gcnt, 1);
                cand[p] = ((u64)kb << 32) | (u32)(0xFFFFFFFFu - (u32)i);
            }
        }
        __syncthreads();
        const int G = sh_gcnt;   // == PRE_K - need
        u32* scr = (u32*)boxbuf; // boxes not gathered yet
        int lo = tid * 32; if (lo > N_TOT) lo = N_TOT;
        int hi = lo + 32;  if (hi > N_TOT) hi = N_TOT;
        int lc = 0;
        for (int i = lo; i < hi; ++i)
            if (skey[i] == (u16)t16 &&
                __float_as_uint(score_f32(i, b, c, p3, p4, p5)) == thr) ++lc;
        u32* sc_cur = scr; u32* sc_oth = scr + 512;
        sc_cur[tid] = (u32)lc;
        __syncthreads();
        for (int off = 1; off < NTHR; off <<= 1) {
            sc_oth[tid] = sc_cur[tid] + ((tid >= off) ? sc_cur[tid - off] : 0u);
            __syncthreads();
            u32* tmp = sc_cur; sc_cur = sc_oth; sc_oth = tmp;
        }
        int r = (int)sc_cur[tid] - lc;
        for (int i = lo; i < hi; ++i) {
            if (skey[i] == (u16)t16 &&
                __float_as_uint(score_f32(i, b, c, p3, p4, p5)) == thr) {
                if (r < need) cand[G + r] = ((u64)thr << 32) | (u32)(0xFFFFFFFFu - (u32)i);
                ++r;
            }
        }
        __syncthreads();
        for (int t = PRE_K + tid; t < CAP; t += NTHR) cand[t] = 0ull;
    }
    __syncthreads();

    sort512(cand, tid);

    // ---- gather top-400 boxes (SoA, padded to 448)
    const float4* btab = (const float4*)boxes;
    for (int t = tid; t < 448; t += NTHR) {
        float y1 = 0.f, x1 = 0.f, y2 = 0.f, x2 = 0.f;
        if (t < PRE_K) {
            u64 key = cand[t];
            if ((key >> 32) != 0ull) {
                int idx = (int)(0xFFFFFFFFu - (u32)(key & 0xFFFFFFFFull));
                float4 bb = btab[b * N_TOT + idx];
                y1 = bb.x; x1 = bb.y; y2 = bb.z; x2 = bb.w;
            }
        }
        by1[t] = y1; bx1[t] = x1; by2[t] = y2; bx2[t] = x2;
        bar[t] = (y2 - y1) * (x2 - x1);
    }
    if (tid < 16) keepb[tid] = (tid < 12) ? 0xFFFFFFFFu : ((tid == 12) ? 0xFFFFu : 0u);
    __syncthreads();

    // ---- blocked NMS: per 64-row chunk {parallel diag build, register-serial
    //      diagonal greedy, parallel apply to later columns}
    for (int ch = 0; ch < 7; ++ch) {
        const int rbase = ch << 6;
        // row boxes for this chunk in regs (lane <-> row rbase+lane)
        const float ry1 = by1[rbase + lane], rx1v = bx1[rbase + lane];
        const float ry2 = by2[rbase + lane], rx2v = bx2[rbase + lane];
        const float ra  = bar[rbase + lane];

        // (1) diagonal block build: wave wv builds columns jl = wv*8+q
#pragma unroll
        for (int q = 0; q < 8; ++q) {
            const int jl = wv * 8 + q;
            const int jj = rbase + jl;
            u64 m = 0ull;
            if (jj < PRE_K && ((keepb[jj >> 5] >> (jj & 31)) & 1u)) {
                float cy1 = by1[jj], cx1 = bx1[jj], cy2 = by2[jj], cx2 = bx2[jj], ca = bar[jj];
                float ty = fmaxf(ry1, cy1), tx = fmaxf(rx1v, cx1);
                float byv = fminf(ry2, cy2), rxv = fminf(rx2v, cx2);
                float inter = fmaxf(byv - ty, 0.f) * fmaxf(rxv - tx, 0.f);
                float uni = ra + ca - inter;
                bool o = (lane < jl) && ((inter / fmaxf(uni, 1e-9f)) > NMS_T);
                m = __ballot(o);
            }
            if (lane == 0) diagbuf[jl] = m;
        }
        __syncthreads();

        // (2) serial diagonal greedy: wave 0, registers only
        if (tid < 64) {
            u64 dg = diagbuf[lane];
            int ri = rbase + lane;
            int alive = (ri < PRE_K) ? (int)((keepb[ri >> 5] >> (ri & 31)) & 1u) : 0;
            u64 M = __ballot(alive != 0);
            for (int i = 0; i < 64; ++i) {
                if ((M >> i) & 1ull) {
                    int kill = (int)((dg >> i) & 1ull);
                    alive &= ~kill;
                    M = __ballot(alive != 0);
                }
            }
            if (lane == 0) {
                sh_keptM = M;
                keepb[2 * ch]     = (u32)(M & 0xFFFFFFFFull);
                keepb[2 * ch + 1] = (u32)(M >> 32);
            }
        }
        __syncthreads();

        // (3) parallel apply to later columns
        {
            const u64 keptM = sh_keptM;
            if (keptM != 0ull) {
                for (int jj = rbase + 64 + wv; jj < PRE_K; jj += 8) {
                    if ((keepb[jj >> 5] >> (jj & 31)) & 1u) {
                        float cy1 = by1[jj], cx1 = bx1[jj], cy2 = by2[jj], cx2 = bx2[jj], ca = bar[jj];
                        float ty = fmaxf(ry1, cy1), tx = fmaxf(rx1v, cx1);
                        float byv = fminf(ry2, cy2), rxv = fminf(rx2v, cx2);
                        float inter = fmaxf(byv - ty, 0.f) * fmaxf(rxv - tx, 0.f);
                        float uni = ra + ca - inter;
                        bool o = (inter / fmaxf(uni, 1e-9f)) > NMS_T;
                        u64 m = __ballot(o);
                        if ((m & keptM) != 0ull && lane == 0)
                            atomicAnd(&keepb[jj >> 5], ~(1u << (jj & 31)));
                    }
                }
            }
        }
        __syncthreads();
    }

    if (tid == 0) {
        int acc = 0;
        for (int w = 0; w < 14; ++w) { wpre14[w] = acc; acc += __popc(keepb[w]); }
        sh_ncnt = acc < KEEP_CAP ? acc : KEEP_CAP;
    }
    __syncthreads();

    // ---- compact kept (rank via popcount), cap 200, zero-pad
    const int blk_out = b * NCLS + c;
    float* osc = ksc + (long)blk_out * KEEP_CAP;
    float* obx = kbox + (long)blk_out * KEEP_CAP * 4;
    for (int t = tid; t < PRE_K; t += NTHR) {
        u32 kw = keepb[t >> 5];
        if ((kw >> (t & 31)) & 1u) {
            int pos = wpre14[t >> 5] + __popc(kw & ((1u << (t & 31)) - 1u));
            if (pos < KEEP_CAP) {
                osc[pos] = __uint_as_float((u32)(cand[t] >> 32));
                obx[pos * 4 + 0] = by1[t]; obx[pos * 4 + 1] = bx1[t];
                obx[pos * 4 + 2] = by2[t]; obx[pos * 4 + 3] = bx2[t];
            }
        }
    }
    for (int t = sh_ncnt + tid; t < KEEP_CAP; t += NTHR) {
        osc[t] = 0.0f;
        obx[t * 4 + 0] = 0.f; obx[t * 4 + 1] = 0.f;
        obx[t * 4 + 2] = 0.f; obx[t * 4 + 3] = 0.f;
    }
}

// ---- f32-key radix top-K (used by final_topk over compacted scores)
__device__ __forceinline__ void radix_topk_sort_f32(
    const u32* __restrict__ keys, int n, int K,
    u64* cand, u32* hist, u32* scr,
    u32* sh_dg, u32* sh_S1, u32* sh_T, int* sh_gcnt, int tid)
{
    int need = K;
    digit_select(hist, need, sh_dg, sh_S1, sh_T, tid);
    u32 thr = *sh_dg; need -= (int)*sh_S1;
    int C = (K - need) + (int)*sh_T;
    int eshift = 24;

    const uint4* k4 = (const uint4*)keys;
    const int n4 = n >> 2;
    const int nIter = (n4 + NTHR - 1) / NTHR;

    for (int shift = 16; shift >= 0 && C > CAP; shift -= 8) {
        if (tid < 256) hist[tid] = 0u;
        __syncthreads();
        for (int it = 0; it < nIter; ++it) {
            int i4 = tid + it * NTHR;
            if (i4 < n4) {
                uint4 kk = k4[i4];
                if ((kk.x >> (shift + 8)) == thr) atomicAdd(&hist[(kk.x >> shift) & 255u], 1u);
                if ((kk.y >> (shift + 8)) == thr) atomicAdd(&hist[(kk.y >> shift) & 255u], 1u);
                if ((kk.z >> (shift + 8)) == thr) atomicAdd(&hist[(kk.z >> shift) & 255u], 1u);
                if ((kk.w >> (shift + 8)) == thr) atomicAdd(&hist[(kk.w >> shift) & 255u], 1u);
            }
        }
        __syncthreads();
        digit_select(hist, need, sh_dg, sh_S1, sh_T, tid);
        thr = (thr << 8) | *sh_dg; need -= (int)*sh_S1;
        C = (K - need) + (int)*sh_T;
        eshift = shift;
    }

    if (C <= CAP) {
        for (int it = 0; it < nIter; ++it) {
            int i4 = tid + it * NTHR;
            if (i4 < n4) {
                uint4 kk = k4[i4];
                int i0 = i4 << 2;
                if ((kk.x >> eshift) >= thr) { int p = atomicAdd(sh_gcnt, 1); cand[p] = ((u64)kk.x << 32) | (u32)(0xFFFFFFFFu - (u32)(i0 + 0)); }
                if ((kk.y >> eshift) >= thr) { int p = atomicAdd(sh_gcnt, 1); cand[p] = ((u64)kk.y << 32) | (u32)(0xFFFFFFFFu - (u32)(i0 + 1)); }
                if ((kk.z >> eshift) >= thr) { int p = atomicAdd(sh_gcnt, 1); cand[p] = ((u64)kk.z << 32) | (u32)(0xFFFFFFFFu - (u32)(i0 + 2)); }
                if ((kk.w >> eshift) >= thr) { int p = atomicAdd(sh_gcnt, 1); cand[p] = ((u64)kk.w << 32) | (u32)(0xFFFFFFFFu - (u32)(i0 + 3)); }
            }
        }
        __syncthreads();
        for (int t = C + tid; t < CAP; t += NTHR) cand[t] = 0ull;
    } else {
        for (int i = tid; i < n; i += NTHR) {
            u32 k = keys[i];
            if (k > thr) {
                int p = atomicAdd(sh_gcnt, 1);
                cand[p] = ((u64)k << 32) | (u32)(0xFFFFFFFFu - (u32)i);
            }
        }
        __syncthreads();
        const int G = *sh_gcnt;
        int lo = tid * 32; if (lo > n) lo = n;
        int hi = lo + 32;  if (hi > n) hi = n;
        int lc = 0;
        for (int i = lo; i < hi; ++i) if (keys[i] == thr) ++lc;
        u32* sc_cur = scr; u32* sc_oth = scr + 512;
        sc_cur[tid] = (u32)lc;
        __syncthreads();
        for (int off = 1; off < NTHR; off <<= 1) {
            sc_oth[tid] = sc_cur[tid] + ((tid >= off) ? sc_cur[tid - off] : 0u);
            __syncthreads();
            u32* tmp = sc_cur; sc_cur = sc_oth; sc_oth = tmp;
        }
        int r = (int)sc_cur[tid] - lc;
        for (int i = lo; i < hi; ++i) {
            if (keys[i] == thr) {
                if (r < need) cand[G + r] = ((u64)thr << 32) | (u32)(0xFFFFFFFFu - (u32)i);
                ++r;
            }
        }
        __syncthreads();
        for (int t = K + tid; t < CAP; t += NTHR) cand[t] = 0ull;
    }
    __syncthreads();
    sort512(cand, tid);
}

// ---- Stage 3: per image top-200 over 16000 compacted candidates -> outputs
__global__ __launch_bounds__(NTHR) void final_topk_kernel(
    const float* __restrict__ ksc, const float* __restrict__ kbox,
    float* __restrict__ out)
{
    __shared__ alignas(16) u64 cand[CAP];
    __shared__ u32 hist[260];
    __shared__ u32 scr[1024];
    __shared__ u32 sh_dg, sh_S1, sh_T;
    __shared__ int sh_gcnt;

    const int tid = threadIdx.x;
    const int lane = tid & 63;
    const int b = blockIdx.x;
    const u32* keys = (const u32*)(ksc + (long)b * M_FIN);

    if (tid < 260) hist[tid] = 0u;
    if (tid == 0) sh_gcnt = 0;
    __syncthreads();
    const uint4* k4 = (const uint4*)keys;
#pragma unroll
    for (int it = 0; it < 8; ++it) {
        int i4 = tid + it * NTHR;
        bool v = i4 < (M_FIN >> 2);
        u32 d0 = 0, d1 = 0, d2 = 0, d3 = 0;
        if (v) {
            uint4 kk = k4[i4];
            d0 = kk.x >> 24; d1 = kk.y >> 24; d2 = kk.z >> 24; d3 = kk.w >> 24;
        }
        hist_agg(hist, d0, v, lane);
        hist_agg(hist, d1, v, lane);
        hist_agg(hist, d2, v, lane);
        hist_agg(hist, d3, v, lane);
    }
    __syncthreads();

    radix_topk_sort_f32(keys, M_FIN, MAX_BOXES, cand, hist, scr,
                        &sh_dg, &sh_S1, &sh_T, &sh_gcnt, tid);

    float* obb = out;                         // (8,200,4)
    float* ocf = out + 8 * MAX_BOXES * 4;     // (8,200)
    float* ocl = ocf + 8 * MAX_BOXES;         // (8,200)
    float* onm = ocl + 8 * MAX_BOXES;         // (8,)

    float s = 0.f;
    if (tid < MAX_BOXES) {
        u64 key = cand[tid];
        s = __uint_as_float((u32)(key >> 32));
        float y1 = 0.f, x1 = 0.f, y2 = 0.f, x2 = 0.f, cid = 0.f;
        if (s > 0.0f) {
            int i = (int)(0xFFFFFFFFu - (u32)(key & 0xFFFFFFFFull));
            int cc = i / KEEP_CAP, j = i % KEEP_CAP;
            const float* bb = kbox + (((long)b * NCLS + cc) * KEEP_CAP + j) * 4;
            y1 = bb[0]; x1 = bb[1]; y2 = bb[2]; x2 = bb[3];
            cid = (float)cc;
        }
        long o = (long)b * MAX_BOXES + tid;
        obb[o * 4 + 0] = y1; obb[o * 4 + 1] = x1; obb[o * 4 + 2] = y2; obb[o * 4 + 3] = x2;
        ocf[o] = s; ocl[o] = cid;
    }
    int cnt = __syncthreads_count(tid < MAX_BOXES && s > 0.0f);
    if (tid == 0) onm[b] = (float)cnt;
}

extern "C" void kernel_launch(void* const* d_in, const int* in_sizes, int n_in,
                              void* d_out, int out_size, void* d_ws, size_t ws_size,
                              hipStream_t stream) {
    const float* p3 = (const float*)d_in[0];
    const float* p4 = (const float*)d_in[1];
    const float* p5 = (const float*)d_in[2];
    const float* a3 = (const float*)d_in[3];
    const float* a4 = (const float*)d_in[4];
    const float* a5 = (const float*)d_in[5];
    float* out = (float*)d_out;

    const size_t s16_bytes  = (size_t)8 * NCLS * N_TOT * 2;      // 20,643,840
    const size_t box_bytes  = (size_t)8 * N_TOT * 16;            //  2,064,384
    const size_t ksc_bytes  = (size_t)8 * NCLS * KEEP_CAP * 4;   //    512,000

    u16*   scores16 = (u16*)d_ws;
    float* boxes    = (float*)((char*)d_ws + s16_bytes);
    float* ksc      = (float*)((char*)d_ws + s16_bytes + box_bytes);
    float* kbox     = (float*)((char*)d_ws + s16_bytes + box_bytes + ksc_bytes);

    decode_kernel<<<504, 256, 0, stream>>>(p3, p4, p5, a3, a4, a5, scores16, boxes);
    topk_nms_fused<<<8 * NCLS, NTHR, 0, stream>>>(scores16, boxes, p3, p4, p5, ksc, kbox);
    final_topk_kernel<<<8, NTHR, 0, stream>>>(ksc, kbox, out);
}

// Round 9
// 168.888 us; speedup vs baseline: 1.2074x; 1.0003x over previous
//
#include <hip/hip_runtime.h>
#include <math.h>

#define NCLS 80
#define PRE_K 400
#define MAX_BOXES 200
#define KEEP_CAP 200
#define N_TOT 16128
#define M_FIN (NCLS * KEEP_CAP)   // 16000
#define NMS_T 0.6f
#define NTHR 512
#define CAP 512                    // candidate buffer (>= K + tie margin)

typedef unsigned long long u64;
typedef unsigned int u32;
typedef unsigned short u16;

__device__ __forceinline__ float sigf(float x) { return 1.0f / (1.0f + expf(-x)); }

// exact score recompute — bitwise-identical expression to decode_kernel's store
__device__ __forceinline__ float score_f32(int idx, int b, int c,
    const float* __restrict__ p3, const float* __restrict__ p4, const float* __restrict__ p5)
{
    const float* base; int W, n;
    if (idx < 12288)      { base = p3; W = 64; n = idx; }
    else if (idx < 15360) { base = p4; W = 32; n = idx - 12288; }
    else                  { base = p5; W = 16; n = idx - 15360; }
    int a = n % 3, hw = n / 3, w = hw % W, h = hw / W;
    const float* rec = base + (((b * W + h) * W + w) * 255 + a * 85);
    return sigf(rec[5 + c]) * sigf(rec[4]);
}

// wave-aggregated LDS histogram add: one atomic per distinct digit per wave
__device__ __forceinline__ void hist_agg(u32* hist, u32 d, bool valid, int lane)
{
    u64 act = __ballot(valid);
    while (act) {
        int ldr = __ffsll((unsigned long long)act) - 1;
        u32 dl = __shfl(d, ldr, 64);
        u64 m = __ballot(valid && d == dl);
        if (lane == ldr) atomicAdd(&hist[dl], (u32)__popcll(m));
        act &= ~m;
    }
}

// hist[256] -> digit d with S_d >= need > S_{d+1}; wave 0 only, 1 barrier.
__device__ __forceinline__ void digit_select(const u32* hist, int need,
                                             u32* sh_dg, u32* sh_S1, u32* sh_T, int tid)
{
    if (tid < 64) {
        const int lane = tid;
        u32 h0 = hist[4 * lane + 0], h1 = hist[4 * lane + 1];
        u32 h2 = hist[4 * lane + 2], h3 = hist[4 * lane + 3];
        u32 loc = h0 + h1 + h2 + h3;
        u32 s = loc;
#pragma unroll
        for (int off = 1; off < 64; off <<= 1) {
            u32 t = __shfl_down(s, off, 64);
            if (lane + off < 64) s += t;
        }
        u32 after = s - loc;
        u32 S3 = h3 + after, S2 = h2 + S3, S1v = h1 + S2, S0 = h0 + S1v;
        u32 Sarr[5] = { S0, S1v, S2, S3, after };
#pragma unroll
        for (int k = 0; k < 4; ++k) {
            if ((int)Sarr[k] >= need && need > (int)Sarr[k + 1]) {
                *sh_dg = (u32)(4 * lane + k);
                *sh_S1 = Sarr[k + 1];
                *sh_T  = Sarr[k] - Sarr[k + 1];
            }
        }
    }
    __syncthreads();
}

// bitonic sort CAP=512 desc over LDS cand, one elem/thread; k<=64 stages in-wave
__device__ __forceinline__ void sort512(u64* cand, int tid)
{
    u64 v = cand[tid];
#pragma unroll
    for (int k2 = 2; k2 <= 64; k2 <<= 1) {
#pragma unroll
        for (int j = k2 >> 1; j > 0; j >>= 1) {
            u64 p = __shfl_xor(v, j, 64);
            bool takeMax = ((tid & k2) == 0) ^ ((tid & j) != 0);
            v = takeMax ? (v >= p ? v : p) : (v <= p ? v : p);
        }
    }
    for (int k2 = 128; k2 <= CAP; k2 <<= 1) {
        for (int j = k2 >> 1; j >= 64; j >>= 1) {
            __syncthreads();
            cand[tid] = v;
            __syncthreads();
            u64 p = cand[tid ^ j];
            bool takeMax = ((tid & k2) == 0) ^ ((tid & j) != 0);
            v = takeMax ? (v >= p ? v : p) : (v <= p ? v : p);
        }
#pragma unroll
        for (int j = 32; j > 0; j >>= 1) {
            u64 p = __shfl_xor(v, j, 64);
            bool takeMax = ((tid & k2) == 0) ^ ((tid & j) != 0);
            v = takeMax ? (v >= p ? v : p) : (v <= p ? v : p);
        }
    }
    __syncthreads();
    cand[tid] = v;
    __syncthreads();
}

// ---- Stage 1: decode u16 score keys [b][c][n] + clipped boxes float4[b][n]
__global__ __launch_bounds__(256) void decode_kernel(
    const float* __restrict__ p3, const float* __restrict__ p4, const float* __restrict__ p5,
    const float* __restrict__ a3, const float* __restrict__ a4, const float* __restrict__ a5,
    u16* __restrict__ scores16, float* __restrict__ boxes)
{
    const int blk = blockIdx.x;
    const int b = blk & 7;
    const int n = ((blk >> 3) << 8) + threadIdx.x;

    const float* base; const float* anc; int logw, nn; float sx;
    if (n < 12288)      { base = p3; anc = a3; logw = 6; nn = n;         sx = 1.2f;  }
    else if (n < 15360) { base = p4; anc = a4; logw = 5; nn = n - 12288; sx = 1.1f;  }
    else                { base = p5; anc = a5; logw = 4; nn = n - 15360; sx = 1.05f; }
    const int W = 1 << logw;
    const int a = nn % 3; const int hw = nn / 3;
    const int w = hw & (W - 1); const int h = hw >> logw;
    const float winv = 1.0f / (float)W;
    const float* rec = base + ((size_t)((b * W + h) * W + w) * 255 + a * 85);

    float tx = rec[0], ty = rec[1], tw = rec[2], th = rec[3], to = rec[4];
    float sobj = sigf(to);
    float cx = (sigf(tx) * sx - 0.5f * (sx - 1.0f) + (float)w) * winv;
    float cy = (sigf(ty) * sx - 0.5f * (sx - 1.0f) + (float)h) * winv;
    float bw = expf(tw) * anc[a * 2 + 0] * (1.0f / 512.0f);   // W*stride == 512 all levels
    float bh = expf(th) * anc[a * 2 + 1] * (1.0f / 512.0f);
    float x1 = cx - 0.5f * bw, x2 = cx + 0.5f * bw;
    float y1 = cy - 0.5f * bh, y2 = cy + 0.5f * bh;
    y1 = fminf(fmaxf(y1, 0.f), 1.f); x1 = fminf(fmaxf(x1, 0.f), 1.f);
    y2 = fminf(fmaxf(y2, 0.f), 1.f); x2 = fminf(fmaxf(x2, 0.f), 1.f);
    float4 bb; bb.x = y1; bb.y = x1; bb.z = y2; bb.w = x2;
    ((float4*)boxes)[b * N_TOT + n] = bb;

    u16* sb = scores16 + (long)b * NCLS * N_TOT + n;
#pragma unroll 8
    for (int cc = 0; cc < NCLS; ++cc)
        sb[(long)cc * N_TOT] = (u16)(__float_as_uint(sigf(rec[5 + cc]) * sobj) >> 16);
}

// ---- Stage 2: per (image,class) u16-radix top-400 -> sort -> blocked NMS
__global__ __launch_bounds__(NTHR, 4) void topk_nms_fused(
    const u16* __restrict__ scores16, const float* __restrict__ boxes,
    const float* __restrict__ p3, const float* __restrict__ p4, const float* __restrict__ p5,
    float* __restrict__ ksc, float* __restrict__ kbox)
{
    __shared__ alignas(16) u16 skey[N_TOT];          // 32256 B staged keys
    __shared__ alignas(16) u64 cand[CAP];            // 4096 B
    __shared__ u32 hist[260];                        // 1040 B
    __shared__ u32 sh_dg, sh_S1, sh_T;
    __shared__ int sh_gcnt;
    __shared__ alignas(16) float boxbuf[5 * 448];    // 8960 B (also lvl-4 trim scratch)
    __shared__ alignas(16) u64 diagbuf[64];          // 512 B
    __shared__ u32 keepb[16];                        // 448 keep bits (14 words used)
    __shared__ u64 sh_keptM;
    __shared__ int wpre14[14];
    __shared__ int sh_ncnt;

    float* by1 = boxbuf;
    float* bx1 = boxbuf + 448;
    float* by2 = boxbuf + 896;
    float* bx2 = boxbuf + 1344;
    float* bar = boxbuf + 1792;

    const int tid = threadIdx.x;
    const int wv = tid >> 6;
    const int lane = tid & 63;
    const int b = blockIdx.x & 7;     // all 80 class-blocks of an image on one XCD
    const int c = blockIdx.x >> 3;

    const u16* keys16g = scores16 + (long)(b * NCLS + c) * N_TOT;
    const uint4* k4g = (const uint4*)keys16g;
    const uint4* k4 = (const uint4*)skey;       // LDS view, 8 u16 per uint4
    const int N8 = N_TOT >> 3;                  // 2016

    // ---- Phase A: stage to LDS + pass-1 histogram (hi byte, wave-aggregated)
    if (tid < 260) hist[tid] = 0u;
    if (tid == 0) sh_gcnt = 0;
    __syncthreads();
#pragma unroll
    for (int it = 0; it < 4; ++it) {
        int i4 = tid + it * NTHR;
        bool v = i4 < N8;
        u32 e0 = 0, e1 = 0, e2 = 0, e3 = 0, e4 = 0, e5 = 0, e6 = 0, e7 = 0;
        if (v) {
            uint4 kk = k4g[i4];
            ((uint4*)skey)[i4] = kk;
            e0 = kk.x & 0xffffu; e1 = kk.x >> 16; e2 = kk.y & 0xffffu; e3 = kk.y >> 16;
            e4 = kk.z & 0xffffu; e5 = kk.z >> 16; e6 = kk.w & 0xffffu; e7 = kk.w >> 16;
        }
        hist_agg(hist, e0 >> 8, v, lane); hist_agg(hist, e1 >> 8, v, lane);
        hist_agg(hist, e2 >> 8, v, lane); hist_agg(hist, e3 >> 8, v, lane);
        hist_agg(hist, e4 >> 8, v, lane); hist_agg(hist, e5 >> 8, v, lane);
        hist_agg(hist, e6 >> 8, v, lane); hist_agg(hist, e7 >> 8, v, lane);
    }
    __syncthreads();

    int need = PRE_K;
    digit_select(hist, need, &sh_dg, &sh_S1, &sh_T, tid);
    u32 thr = sh_dg; need -= (int)sh_S1;
    int C = (PRE_K - need) + (int)sh_T;
    int lvl = 1;

    // ---- pass 2: low byte among hi==thr (spread -> direct atomics), LDS scan
    if (C > CAP) {
        if (tid < 256) hist[tid] = 0u;
        __syncthreads();
#pragma unroll
        for (int it = 0; it < 4; ++it) {
            int i4 = tid + it * NTHR;
            if (i4 < N8) {
                uint4 kk = k4[i4];
                u32 e[8] = { kk.x & 0xffffu, kk.x >> 16, kk.y & 0xffffu, kk.y >> 16,
                             kk.z & 0xffffu, kk.z >> 16, kk.w & 0xffffu, kk.w >> 16 };
#pragma unroll
                for (int q = 0; q < 8; ++q)
                    if ((e[q] >> 8) == thr) atomicAdd(&hist[e[q] & 255u], 1u);
            }
        }
        __syncthreads();
        digit_select(hist, need, &sh_dg, &sh_S1, &sh_T, tid);
        thr = (thr << 8) | sh_dg; need -= (int)sh_S1;
        C = (PRE_K - need) + (int)sh_T;
        lvl = 2;
    }

    // ---- pass 3 (rare): refine with recomputed f32 bits [15:8]
    if (C > CAP) {
        u32 t16 = thr;
        if (tid < 256) hist[tid] = 0u;
        __syncthreads();
        for (int i = tid; i < N_TOT; i += NTHR) {
            if (skey[i] == (u16)t16) {
                u32 kb = __float_as_uint(score_f32(i, b, c, p3, p4, p5));
                atomicAdd(&hist[(kb >> 8) & 255u], 1u);
            }
        }
        __syncthreads();
        digit_select(hist, need, &sh_dg, &sh_S1, &sh_T, tid);
        thr = (thr << 8) | sh_dg; need -= (int)sh_S1;
        C = (PRE_K - need) + (int)sh_T;
        lvl = 3;
    }

    // ---- pass 4 (rare): full 32-bit
    if (C > CAP) {
        u32 t16 = thr >> 8;
        if (tid < 256) hist[tid] = 0u;
        __syncthreads();
        for (int i = tid; i < N_TOT; i += NTHR) {
            if (skey[i] == (u16)t16) {
                u32 kb = __float_as_uint(score_f32(i, b, c, p3, p4, p5));
                if ((kb >> 8) == thr) atomicAdd(&hist[kb & 255u], 1u);
            }
        }
        __syncthreads();
        digit_select(hist, need, &sh_dg, &sh_S1, &sh_T, tid);
        thr = (thr << 8) | sh_dg; need -= (int)sh_S1;
        C = (PRE_K - need) + (int)sh_T;
        lvl = 4;
    }

    // ---- collect candidates (superset ok; sort trims exactly)
    if (lvl <= 2) {
#pragma unroll
        for (int it = 0; it < 4; ++it) {
            int i4 = tid + it * NTHR;
            if (i4 < N8) {
                uint4 kk = k4[i4];
                int i0 = i4 << 3;
                u32 e[8] = { kk.x & 0xffffu, kk.x >> 16, kk.y & 0xffffu, kk.y >> 16,
                             kk.z & 0xffffu, kk.z >> 16, kk.w & 0xffffu, kk.w >> 16 };
#pragma unroll
                for (int q = 0; q < 8; ++q) {
                    bool take = (lvl == 1) ? ((e[q] >> 8) >= thr) : (e[q] >= thr);
                    if (take) {
                        int p = atomicAdd(&sh_gcnt, 1);
                        int i = i0 + q;
                        u32 kb = __float_as_uint(score_f32(i, b, c, p3, p4, p5));
                        cand[p] = ((u64)kb << 32) | (u32)(0xFFFFFFFFu - (u32)i);
                    }
                }
            }
        }
        __syncthreads();
        for (int t = C + tid; t < CAP; t += NTHR) cand[t] = 0ull;
    } else if (C <= CAP) {
        u32 t16 = (lvl == 3) ? (thr >> 8) : (thr >> 16);
        for (int i = tid; i < N_TOT; i += NTHR) {
            u32 k = skey[i];
            bool take = false;
            u32 kb = 0;
            if (k > t16) { take = true; kb = __float_as_uint(score_f32(i, b, c, p3, p4, p5)); }
            else if (k == t16) {
                kb = __float_as_uint(score_f32(i, b, c, p3, p4, p5));
                take = (lvl == 3) ? ((kb >> 8) >= thr) : (kb >= thr);
            }
            if (take) {
                int p = atomicAdd(&sh_gcnt, 1);
                cand[p] = ((u64)kb << 32) | (u32)(0xFFFFFFFFu - (u32)i);
            }
        }
        __syncthreads();
        for (int t = C + tid; t < CAP; t += NTHR) cand[t] = 0ull;
    } else {
        // lvl==4 and >CAP ties at one exact f32 value: index-rank trim
        u32 t16 = thr >> 16;
        for (int i = tid; i < N_TOT; i += NTHR) {
            u32 k = skey[i];
            if (k < t16) continue;
            u32 kb = __float_as_uint(score_f32(i, b, c, p3, p4, p5));
            if (kb > thr) {
                int p = atomicAdd(&sh_gcnt, 1);
                cand[p] = ((u64)kb << 32) | (u32)(0xFFFFFFFFu - (u32)i);
            }
        }
        __syncthreads();
        const int G = sh_gcnt;   // == PRE_K - need
        u32* scr = (u32*)boxbuf; // boxes not gathered yet
        int lo = tid * 32; if (lo > N_TOT) lo = N_TOT;
        int hi = lo + 32;  if (hi > N_TOT) hi = N_TOT;
        int lc = 0;
        for (int i = lo; i < hi; ++i)
            if (skey[i] == (u16)t16 &&
                __float_as_uint(score_f32(i, b, c, p3, p4, p5)) == thr) ++lc;
        u32* sc_cur = scr; u32* sc_oth = scr + 512;
        sc_cur[tid] = (u32)lc;
        __syncthreads();
        for (int off = 1; off < NTHR; off <<= 1) {
            sc_oth[tid] = sc_cur[tid] + ((tid >= off) ? sc_cur[tid - off] : 0u);
            __syncthreads();
            u32* tmp = sc_cur; sc_cur = sc_oth; sc_oth = tmp;
        }
        int r = (int)sc_cur[tid] - lc;
        for (int i = lo; i < hi; ++i) {
            if (skey[i] == (u16)t16 &&
                __float_as_uint(score_f32(i, b, c, p3, p4, p5)) == thr) {
                if (r < need) cand[G + r] = ((u64)thr << 32) | (u32)(0xFFFFFFFFu - (u32)i);
                ++r;
            }
        }
        __syncthreads();
        for (int t = PRE_K + tid; t < CAP; t += NTHR) cand[t] = 0ull;
    }
    __syncthreads();

    sort512(cand, tid);

    // ---- gather top-400 boxes (SoA, padded to 448)
    const float4* btab = (const float4*)boxes;
    for (int t = tid; t < 448; t += NTHR) {
        float y1 = 0.f, x1 = 0.f, y2 = 0.f, x2 = 0.f;
        if (t < PRE_K) {
            u64 key = cand[t];
            if ((key >> 32) != 0ull) {
                int idx = (int)(0xFFFFFFFFu - (u32)(key & 0xFFFFFFFFull));
                float4 bb = btab[b * N_TOT + idx];
                y1 = bb.x; x1 = bb.y; y2 = bb.z; x2 = bb.w;
            }
        }
        by1[t] = y1; bx1[t] = x1; by2[t] = y2; bx2[t] = x2;
        bar[t] = (y2 - y1) * (x2 - x1);
    }
    if (tid < 16) keepb[tid] = (tid < 12) ? 0xFFFFFFFFu : ((tid == 12) ? 0xFFFFu : 0u);
    __syncthreads();

    // ---- blocked NMS: per 64-row chunk {parallel diag build, register-serial
    //      diagonal greedy, parallel apply to later columns}
    for (int ch = 0; ch < 7; ++ch) {
        const int rbase = ch << 6;
        // row boxes for this chunk in regs (lane <-> row rbase+lane)
        const float ry1 = by1[rbase + lane], rx1v = bx1[rbase + lane];
        const float ry2 = by2[rbase + lane], rx2v = bx2[rbase + lane];
        const float ra  = bar[rbase + lane];

        // (1) diagonal block build: wave wv builds columns jl = wv*8+q
#pragma unroll
        for (int q = 0; q < 8; ++q) {
            const int jl = wv * 8 + q;
            const int jj = rbase + jl;
            u64 m = 0ull;
            if (jj < PRE_K && ((keepb[jj >> 5] >> (jj & 31)) & 1u)) {
                float cy1 = by1[jj], cx1 = bx1[jj], cy2 = by2[jj], cx2 = bx2[jj], ca = bar[jj];
                float ty = fmaxf(ry1, cy1), tx = fmaxf(rx1v, cx1);
                float byv = fminf(ry2, cy2), rxv = fminf(rx2v, cx2);
                float inter = fmaxf(byv - ty, 0.f) * fmaxf(rxv - tx, 0.f);
                float uni = ra + ca - inter;
                bool o = (lane < jl) && ((inter / fmaxf(uni, 1e-9f)) > NMS_T);
                m = __ballot(o);
            }
            if (lane == 0) diagbuf[jl] = m;
        }
        __syncthreads();

        // (2) serial diagonal greedy: wave 0, registers only
        if (tid < 64) {
            u64 dg = diagbuf[lane];
            int ri = rbase + lane;
            int alive = (ri < PRE_K) ? (int)((keepb[ri >> 5] >> (ri & 31)) & 1u) : 0;
            u64 M = __ballot(alive != 0);
            for (int i = 0; i < 64; ++i) {
                if ((M >> i) & 1ull) {
                    int kill = (int)((dg >> i) & 1ull);
                    alive &= ~kill;
                    M = __ballot(alive != 0);
                }
            }
            if (lane == 0) {
                sh_keptM = M;
                keepb[2 * ch]     = (u32)(M & 0xFFFFFFFFull);
                keepb[2 * ch + 1] = (u32)(M >> 32);
            }
        }
        __syncthreads();

        // (3) parallel apply to later columns
        {
            const u64 keptM = sh_keptM;
            if (keptM != 0ull) {
                for (int jj = rbase + 64 + wv; jj < PRE_K; jj += 8) {
                    if ((keepb[jj >> 5] >> (jj & 31)) & 1u) {
                        float cy1 = by1[jj], cx1 = bx1[jj], cy2 = by2[jj], cx2 = bx2[jj], ca = bar[jj];
                        float ty = fmaxf(ry1, cy1), tx = fmaxf(rx1v, cx1);
                        float byv = fminf(ry2, cy2), rxv = fminf(rx2v, cx2);
                        float inter = fmaxf(byv - ty, 0.f) * fmaxf(rxv - tx, 0.f);
                        float uni = ra + ca - inter;
                        bool o = (inter / fmaxf(uni, 1e-9f)) > NMS_T;
                        u64 m = __ballot(o);
                        if ((m & keptM) != 0ull && lane == 0)
                            atomicAnd(&keepb[jj >> 5], ~(1u << (jj & 31)));
                    }
                }
            }
        }
        __syncthreads();
    }

    if (tid == 0) {
        int acc = 0;
        for (int w = 0; w < 14; ++w) { wpre14[w] = acc; acc += __popc(keepb[w]); }
        sh_ncnt = acc < KEEP_CAP ? acc : KEEP_CAP;
    }
    __syncthreads();

    // ---- compact kept (rank via popcount), cap 200, zero-pad
    const int blk_out = b * NCLS + c;
    float* osc = ksc + (long)blk_out * KEEP_CAP;
    float* obx = kbox + (long)blk_out * KEEP_CAP * 4;
    for (int t = tid; t < PRE_K; t += NTHR) {
        u32 kw = keepb[t >> 5];
        if ((kw >> (t & 31)) & 1u) {
            int pos = wpre14[t >> 5] + __popc(kw & ((1u << (t & 31)) - 1u));
            if (pos < KEEP_CAP) {
                osc[pos] = __uint_as_float((u32)(cand[t] >> 32));
                obx[pos * 4 + 0] = by1[t]; obx[pos * 4 + 1] = bx1[t];
                obx[pos * 4 + 2] = by2[t]; obx[pos * 4 + 3] = bx2[t];
            }
        }
    }
    for (int t = sh_ncnt + tid; t < KEEP_CAP; t += NTHR) {
        osc[t] = 0.0f;
        obx[t * 4 + 0] = 0.f; obx[t * 4 + 1] = 0.f;
        obx[t * 4 + 2] = 0.f; obx[t * 4 + 3] = 0.f;
    }
}

// ---- f32-key radix top-K (used by final_topk over compacted scores)
__device__ __forceinline__ void radix_topk_sort_f32(
    const u32* __restrict__ keys, int n, int K,
    u64* cand, u32* hist, u32* scr,
    u32* sh_dg, u32* sh_S1, u32* sh_T, int* sh_gcnt, int tid)
{
    int need = K;
    digit_select(hist, need, sh_dg, sh_S1, sh_T, tid);
    u32 thr = *sh_dg; need -= (int)*sh_S1;
    int C = (K - need) + (int)*sh_T;
    int eshift = 24;

    const uint4* k4 = (const uint4*)keys;
    const int n4 = n >> 2;
    const int nIter = (n4 + NTHR - 1) / NTHR;

    for (int shift = 16; shift >= 0 && C > CAP; shift -= 8) {
        if (tid < 256) hist[tid] = 0u;
        __syncthreads();
        for (int it = 0; it < nIter; ++it) {
            int i4 = tid + it * NTHR;
            if (i4 < n4) {
                uint4 kk = k4[i4];
                if ((kk.x >> (shift + 8)) == thr) atomicAdd(&hist[(kk.x >> shift) & 255u], 1u);
                if ((kk.y >> (shift + 8)) == thr) atomicAdd(&hist[(kk.y >> shift) & 255u], 1u);
                if ((kk.z >> (shift + 8)) == thr) atomicAdd(&hist[(kk.z >> shift) & 255u], 1u);
                if ((kk.w >> (shift + 8)) == thr) atomicAdd(&hist[(kk.w >> shift) & 255u], 1u);
            }
        }
        __syncthreads();
        digit_select(hist, need, sh_dg, sh_S1, sh_T, tid);
        thr = (thr << 8) | *sh_dg; need -= (int)*sh_S1;
        C = (K - need) + (int)*sh_T;
        eshift = shift;
    }

    if (C <= CAP) {
        for (int it = 0; it < nIter; ++it) {
            int i4 = tid + it * NTHR;
            if (i4 < n4) {
                uint4 kk = k4[i4];
                int i0 = i4 << 2;
                if ((kk.x >> eshift) >= thr) { int p = atomicAdd(sh_gcnt, 1); cand[p] = ((u64)kk.x << 32) | (u32)(0xFFFFFFFFu - (u32)(i0 + 0)); }
                if ((kk.y >> eshift) >= thr) { int p = atomicAdd(sh_gcnt, 1); cand[p] = ((u64)kk.y << 32) | (u32)(0xFFFFFFFFu - (u32)(i0 + 1)); }
                if ((kk.z >> eshift) >= thr) { int p = atomicAdd(sh_gcnt, 1); cand[p] = ((u64)kk.z << 32) | (u32)(0xFFFFFFFFu - (u32)(i0 + 2)); }
                if ((kk.w >> eshift) >= thr) { int p = atomicAdd(sh_gcnt, 1); cand[p] = ((u64)kk.w << 32) | (u32)(0xFFFFFFFFu - (u32)(i0 + 3)); }
            }
        }
        __syncthreads();
        for (int t = C + tid; t < CAP; t += NTHR) cand[t] = 0ull;
    } else {
        for (int i = tid; i < n; i += NTHR) {
            u32 k = keys[i];
            if (k > thr) {
                int p = atomicAdd(sh_gcnt, 1);
                cand[p] = ((u64)k << 32) | (u32)(0xFFFFFFFFu - (u32)i);
            }
        }
        __syncthreads();
        const int G = *sh_gcnt;
        int lo = tid * 32; if (lo > n) lo = n;
        int hi = lo + 32;  if (hi > n) hi = n;
        int lc = 0;
        for (int i = lo; i < hi; ++i) if (keys[i] == thr) ++lc;
        u32* sc_cur = scr; u32* sc_oth = scr + 512;
        sc_cur[tid] = (u32)lc;
        __syncthreads();
        for (int off = 1; off < NTHR; off <<= 1) {
            sc_oth[tid] = sc_cur[tid] + ((tid >= off) ? sc_cur[tid - off] : 0u);
            __syncthreads();
            u32* tmp = sc_cur; sc_cur = sc_oth; sc_oth = tmp;
        }
        int r = (int)sc_cur[tid] - lc;
        for (int i = lo; i < hi; ++i) {
            if (keys[i] == thr) {
                if (r < need) cand[G + r] = ((u64)thr << 32) | (u32)(0xFFFFFFFFu - (u32)i);
                ++r;
            }
        }
        __syncthreads();
        for (int t = K + tid; t < CAP; t += NTHR) cand[t] = 0ull;
    }
    __syncthreads();
    sort512(cand, tid);
}

// ---- Stage 3: per image top-200 over 16000 compacted candidates -> outputs
__global__ __launch_bounds__(NTHR) void final_topk_kernel(
    const float* __restrict__ ksc, const float* __restrict__ kbox,
    float* __restrict__ out)
{
    __shared__ alignas(16) u64 cand[CAP];
    __shared__ u32 hist[260];
    __shared__ u32 scr[1024];
    __shared__ u32 sh_dg, sh_S1, sh_T;
    __shared__ int sh_gcnt;

    const int tid = threadIdx.x;
    const int lane = tid & 63;
    const int b = blockIdx.x;
    const u32* keys = (const u32*)(ksc + (long)b * M_FIN);

    if (tid < 260) hist[tid] = 0u;
    if (tid == 0) sh_gcnt = 0;
    __syncthreads();
    const uint4* k4 = (const uint4*)keys;
#pragma unroll
    for (int it = 0; it < 8; ++it) {
        int i4 = tid + it * NTHR;
        bool v = i4 < (M_FIN >> 2);
        u32 d0 = 0, d1 = 0, d2 = 0, d3 = 0;
        if (v) {
            uint4 kk = k4[i4];
            d0 = kk.x >> 24; d1 = kk.y >> 24; d2 = kk.z >> 24; d3 = kk.w >> 24;
        }
        hist_agg(hist, d0, v, lane);
        hist_agg(hist, d1, v, lane);
        hist_agg(hist, d2, v, lane);
        hist_agg(hist, d3, v, lane);
    }
    __syncthreads();

    radix_topk_sort_f32(keys, M_FIN, MAX_BOXES, cand, hist, scr,
                        &sh_dg, &sh_S1, &sh_T, &sh_gcnt, tid);

    float* obb = out;                         // (8,200,4)
    float* ocf = out + 8 * MAX_BOXES * 4;     // (8,200)
    float* ocl = ocf + 8 * MAX_BOXES;         // (8,200)
    float* onm = ocl + 8 * MAX_BOXES;         // (8,)

    float s = 0.f;
    if (tid < MAX_BOXES) {
        u64 key = cand[tid];
        s = __uint_as_float((u32)(key >> 32));
        float y1 = 0.f, x1 = 0.f, y2 = 0.f, x2 = 0.f, cid = 0.f;
        if (s > 0.0f) {
            int i = (int)(0xFFFFFFFFu - (u32)(key & 0xFFFFFFFFull));
            int cc = i / KEEP_CAP, j = i % KEEP_CAP;
            const float* bb = kbox + (((long)b * NCLS + cc) * KEEP_CAP + j) * 4;
            y1 = bb[0]; x1 = bb[1]; y2 = bb[2]; x2 = bb[3];
            cid = (float)cc;
        }
        long o = (long)b * MAX_BOXES + tid;
        obb[o * 4 + 0] = y1; obb[o * 4 + 1] = x1; obb[o * 4 + 2] = y2; obb[o * 4 + 3] = x2;
        ocf[o] = s; ocl[o] = cid;
    }
    int cnt = __syncthreads_count(tid < MAX_BOXES && s > 0.0f);
    if (tid == 0) onm[b] = (float)cnt;
}

extern "C" void kernel_launch(void* const* d_in, const int* in_sizes, int n_in,
                              void* d_out, int out_size, void* d_ws, size_t ws_size,
                              hipStream_t stream) {
    const float* p3 = (const float*)d_in[0];
    const float* p4 = (const float*)d_in[1];
    const float* p5 = (const float*)d_in[2];
    const float* a3 = (const float*)d_in[3];
    const float* a4 = (const float*)d_in[4];
    const float* a5 = (const float*)d_in[5];
    float* out = (float*)d_out;

    const size_t s16_bytes  = (size_t)8 * NCLS * N_TOT * 2;      // 20,643,840
    const size_t box_bytes  = (size_t)8 * N_TOT * 16;            //  2,064,384
    const size_t ksc_bytes  = (size_t)8 * NCLS * KEEP_CAP * 4;   //    512,000

    u16*   scores16 = (u16*)d_ws;
    float* boxes    = (float*)((char*)d_ws + s16_bytes);
    float* ksc      = (float*)((char*)d_ws + s16_bytes + box_bytes);
    float* kbox     = (float*)((char*)d_ws + s16_bytes + box_bytes + ksc_bytes);

    decode_kernel<<<504, 256, 0, stream>>>(p3, p4, p5, a3, a4, a5, scores16, boxes);
    topk_nms_fused<<<8 * NCLS, NTHR, 0, stream>>>(scores16, boxes, p3, p4, p5, ksc, kbox);
    final_topk_kernel<<<8, NTHR, 0, stream>>>(ksc, kbox, out);
}